// Round 1
// baseline (1126.450 us; speedup 1.0000x reference)
//
#include <hip/hip_runtime.h>

#define NN 50000
#define NE 625000
#define D  128
#define BN 64
#define PAD 36

__global__ __launch_bounds__(256) void zero_agg(float4* __restrict__ agg4) {
    int i = blockIdx.x * blockDim.x + threadIdx.x;
    if (i < NN * D / 4) agg4[i] = float4{0.f, 0.f, 0.f, 0.f};
}

// 32 lanes per edge; lane l handles floats [4l, 4l+4)
__global__ __launch_bounds__(256) void scatter(const float* __restrict__ x,
                                               const int* __restrict__ src,
                                               const int* __restrict__ dst,
                                               const float* __restrict__ ew,
                                               float* __restrict__ agg) {
    int gid  = blockIdx.x * blockDim.x + threadIdx.x;
    int e    = gid >> 5;
    int lane = gid & 31;
    if (e >= NE) return;
    int   s = src[e];
    int   d = dst[e];
    float w = ew[e];
    float4 xv = reinterpret_cast<const float4*>(x + (size_t)s * D)[lane];
    float* ap = agg + (size_t)d * D + lane * 4;
    atomicAdd(ap + 0, xv.x * w);
    atomicAdd(ap + 1, xv.y * w);
    atomicAdd(ap + 2, xv.z * w);
    atomicAdd(ap + 3, xv.w * w);
}

// out[n][o] = relu(sum_k agg[n][k] * W[o][k] + bias[o])
// block: 256 threads, tile 64 nodes x 128 outs, thread tile 4n x 8o
__global__ __launch_bounds__(256) void gemm_bias_relu(const float* __restrict__ agg,
                                                      const float* __restrict__ W,
                                                      const float* __restrict__ bias,
                                                      float* __restrict__ out) {
    __shared__ float As[BN][PAD];   // 9.2 KB
    __shared__ float Ws[D][PAD];    // 18.4 KB
    const int tid   = threadIdx.x;
    const int nbase = blockIdx.x * BN;
    const int tn = tid >> 4;   // 0..15 -> nodes tn*4..tn*4+3
    const int to = tid & 15;   // 0..15 -> outs  to, to+16, ..., to+112

    float acc[4][8];
#pragma unroll
    for (int i = 0; i < 4; ++i)
#pragma unroll
        for (int j = 0; j < 8; ++j) acc[i][j] = 0.f;

    for (int k0 = 0; k0 < D; k0 += 32) {
        // stage A tile: 64 x 32 floats = 512 float4
#pragma unroll
        for (int r = 0; r < 2; ++r) {
            int idx = tid + r * 256;        // 0..511
            int n   = idx >> 3;
            int c4  = (idx & 7) * 4;
            int gn  = nbase + n;
            float4 v = float4{0.f, 0.f, 0.f, 0.f};
            if (gn < NN)
                v = *reinterpret_cast<const float4*>(agg + (size_t)gn * D + k0 + c4);
            *reinterpret_cast<float4*>(&As[n][c4]) = v;
        }
        // stage W tile: 128 x 32 floats = 1024 float4
#pragma unroll
        for (int r = 0; r < 4; ++r) {
            int idx = tid + r * 256;        // 0..1023
            int o   = idx >> 3;
            int c4  = (idx & 7) * 4;
            float4 v = *reinterpret_cast<const float4*>(W + (size_t)o * D + k0 + c4);
            *reinterpret_cast<float4*>(&Ws[o][c4]) = v;
        }
        __syncthreads();

#pragma unroll
        for (int kk = 0; kk < 32; kk += 4) {
            float4 a[4], b[8];
#pragma unroll
            for (int i = 0; i < 4; ++i)
                a[i] = *reinterpret_cast<const float4*>(&As[tn * 4 + i][kk]);
#pragma unroll
            for (int j = 0; j < 8; ++j)
                b[j] = *reinterpret_cast<const float4*>(&Ws[to + 16 * j][kk]);
#pragma unroll
            for (int i = 0; i < 4; ++i)
#pragma unroll
                for (int j = 0; j < 8; ++j)
                    acc[i][j] += a[i].x * b[j].x + a[i].y * b[j].y +
                                 a[i].z * b[j].z + a[i].w * b[j].w;
        }
        __syncthreads();
    }

#pragma unroll
    for (int i = 0; i < 4; ++i) {
        int gn = nbase + tn * 4 + i;
        if (gn >= NN) continue;
#pragma unroll
        for (int j = 0; j < 8; ++j) {
            int o = to + 16 * j;
            float h = acc[i][j] + bias[o];
            out[(size_t)gn * D + o] = h > 0.f ? h : 0.f;
        }
    }
}

extern "C" void kernel_launch(void* const* d_in, const int* in_sizes, int n_in,
                              void* d_out, int out_size, void* d_ws, size_t ws_size,
                              hipStream_t stream) {
    const float* x    = (const float*)d_in[0];
    const int*   eidx = (const int*)d_in[1];   // [2, E] flat: src then dst
    const float* ew   = (const float*)d_in[2];
    const float* W    = (const float*)d_in[3];
    const float* bias = (const float*)d_in[4];
    float* out = (float*)d_out;
    float* agg = (float*)d_ws;                 // NN*D floats = 25.6 MB scratch

    zero_agg<<<(NN * D / 4 + 255) / 256, 256, 0, stream>>>((float4*)agg);
    scatter<<<(NE * 32) / 256, 256, 0, stream>>>(x, eidx, eidx + NE, ew, agg);
    gemm_bias_relu<<<(NN + BN - 1) / BN, 256, 0, stream>>>(agg, W, bias, out);
}

// Round 2
// 196.661 us; speedup vs baseline: 5.7279x; 5.7279x over previous
//
#include <hip/hip_runtime.h>

#define NN 50000
#define NE 625000
#define D  128
#define BN 64
#define PAD 36
#define NBLK 196   // ceil(NN/256)

// ---------------- CSR build ----------------

__global__ __launch_bounds__(256) void zero_counters(int* __restrict__ deg,
                                                     int* __restrict__ fillc) {
    int i = blockIdx.x * blockDim.x + threadIdx.x;
    if (i < NN) { deg[i] = 0; fillc[i] = 0; }
}

__global__ __launch_bounds__(256) void count_deg(const int* __restrict__ dst,
                                                 int* __restrict__ deg) {
    int e = blockIdx.x * blockDim.x + threadIdx.x;
    if (e < NE) atomicAdd(&deg[dst[e]], 1);
}

__global__ __launch_bounds__(256) void scan1(const int* __restrict__ deg,
                                             int* __restrict__ starts,
                                             int* __restrict__ blksum) {
    __shared__ int tmp[256];
    int tid = threadIdx.x;
    int gid = blockIdx.x * 256 + tid;
    int v = (gid < NN) ? deg[gid] : 0;
    tmp[tid] = v; __syncthreads();
#pragma unroll
    for (int off = 1; off < 256; off <<= 1) {
        int t = (tid >= off) ? tmp[tid - off] : 0;
        __syncthreads();
        tmp[tid] += t;
        __syncthreads();
    }
    if (gid < NN) starts[gid] = tmp[tid] - v;       // block-local exclusive
    if (tid == 255) blksum[blockIdx.x] = tmp[255];  // block total
}

__global__ __launch_bounds__(256) void scan2(int* __restrict__ blksum) {
    __shared__ int tmp[256];
    int tid = threadIdx.x;
    int v = (tid < NBLK) ? blksum[tid] : 0;
    tmp[tid] = v; __syncthreads();
#pragma unroll
    for (int off = 1; off < 256; off <<= 1) {
        int t = (tid >= off) ? tmp[tid - off] : 0;
        __syncthreads();
        tmp[tid] += t;
        __syncthreads();
    }
    blksum[tid] = tmp[tid] - v;                      // exclusive block offsets
}

__global__ __launch_bounds__(256) void scan3(const int* __restrict__ blksum,
                                             int* __restrict__ starts) {
    int gid = blockIdx.x * 256 + threadIdx.x;
    if (gid < NN) starts[gid] += blksum[blockIdx.x];
    if (gid == 0) starts[NN] = NE;
}

__global__ __launch_bounds__(256) void fill_csr(const int* __restrict__ src,
                                                const int* __restrict__ dst,
                                                const float* __restrict__ ew,
                                                const int* __restrict__ starts,
                                                int* __restrict__ fillc,
                                                int2* __restrict__ edata) {
    int e = blockIdx.x * blockDim.x + threadIdx.x;
    if (e >= NE) return;
    int d = dst[e];
    int p = atomicAdd(&fillc[d], 1);
    edata[starts[d] + p] = make_int2(src[e], __float_as_int(ew[e]));
}

// ---------------- aggregate (gather) ----------------
// one 64-lane wave per node; lane t owns float2 dims {2t, 2t+1}
__global__ __launch_bounds__(256) void aggregate(const float* __restrict__ x,
                                                 const int* __restrict__ starts,
                                                 const int2* __restrict__ edata,
                                                 float* __restrict__ agg) {
    int node = blockIdx.x * 4 + (threadIdx.x >> 6);
    int t    = threadIdx.x & 63;
    if (node >= NN) return;
    const float2* x2 = reinterpret_cast<const float2*>(x);
    int b = starts[node];
    int e = starts[node + 1];
    float2 acc{0.f, 0.f};
    int i = b;
    for (; i + 1 < e; i += 2) {
        int2 e0 = edata[i], e1 = edata[i + 1];
        float  w0 = __int_as_float(e0.y), w1 = __int_as_float(e1.y);
        float2 v0 = x2[(size_t)e0.x * 64 + t];
        float2 v1 = x2[(size_t)e1.x * 64 + t];
        acc.x += v0.x * w0; acc.y += v0.y * w0;
        acc.x += v1.x * w1; acc.y += v1.y * w1;
    }
    if (i < e) {
        int2 e0 = edata[i];
        float  w0 = __int_as_float(e0.y);
        float2 v0 = x2[(size_t)e0.x * 64 + t];
        acc.x += v0.x * w0; acc.y += v0.y * w0;
    }
    reinterpret_cast<float2*>(agg)[(size_t)node * 64 + t] = acc;
}

// ---------------- GEMM + bias + relu ----------------
__global__ __launch_bounds__(256) void gemm_bias_relu(const float* __restrict__ agg,
                                                      const float* __restrict__ W,
                                                      const float* __restrict__ bias,
                                                      float* __restrict__ out) {
    __shared__ float As[BN][PAD];
    __shared__ float Ws[D][PAD];
    const int tid   = threadIdx.x;
    const int nbase = blockIdx.x * BN;
    const int tn = tid >> 4;
    const int to = tid & 15;

    float acc[4][8];
#pragma unroll
    for (int i = 0; i < 4; ++i)
#pragma unroll
        for (int j = 0; j < 8; ++j) acc[i][j] = 0.f;

    for (int k0 = 0; k0 < D; k0 += 32) {
#pragma unroll
        for (int r = 0; r < 2; ++r) {
            int idx = tid + r * 256;
            int n   = idx >> 3;
            int c4  = (idx & 7) * 4;
            int gn  = nbase + n;
            float4 v = float4{0.f, 0.f, 0.f, 0.f};
            if (gn < NN)
                v = *reinterpret_cast<const float4*>(agg + (size_t)gn * D + k0 + c4);
            *reinterpret_cast<float4*>(&As[n][c4]) = v;
        }
#pragma unroll
        for (int r = 0; r < 4; ++r) {
            int idx = tid + r * 256;
            int o   = idx >> 3;
            int c4  = (idx & 7) * 4;
            float4 v = *reinterpret_cast<const float4*>(W + (size_t)o * D + k0 + c4);
            *reinterpret_cast<float4*>(&Ws[o][c4]) = v;
        }
        __syncthreads();

#pragma unroll
        for (int kk = 0; kk < 32; kk += 4) {
            float4 a[4], b[8];
#pragma unroll
            for (int i = 0; i < 4; ++i)
                a[i] = *reinterpret_cast<const float4*>(&As[tn * 4 + i][kk]);
#pragma unroll
            for (int j = 0; j < 8; ++j)
                b[j] = *reinterpret_cast<const float4*>(&Ws[to + 16 * j][kk]);
#pragma unroll
            for (int i = 0; i < 4; ++i)
#pragma unroll
                for (int j = 0; j < 8; ++j)
                    acc[i][j] += a[i].x * b[j].x + a[i].y * b[j].y +
                                 a[i].z * b[j].z + a[i].w * b[j].w;
        }
        __syncthreads();
    }

#pragma unroll
    for (int i = 0; i < 4; ++i) {
        int gn = nbase + tn * 4 + i;
        if (gn >= NN) continue;
#pragma unroll
        for (int j = 0; j < 8; ++j) {
            int o = to + 16 * j;
            float h = acc[i][j] + bias[o];
            out[(size_t)gn * D + o] = h > 0.f ? h : 0.f;
        }
    }
}

extern "C" void kernel_launch(void* const* d_in, const int* in_sizes, int n_in,
                              void* d_out, int out_size, void* d_ws, size_t ws_size,
                              hipStream_t stream) {
    const float* x    = (const float*)d_in[0];
    const int*   eidx = (const int*)d_in[1];   // [2, E] flat: src then dst
    const float* ew   = (const float*)d_in[2];
    const float* W    = (const float*)d_in[3];
    const float* bias = (const float*)d_in[4];
    float* out = (float*)d_out;

    const int* src = eidx;
    const int* dst = eidx + NE;

    // workspace layout
    char* base = (char*)d_ws;
    float* agg   = (float*)base;                       // NN*D floats = 25.6 MB
    int2*  edata = (int2*)(base + (size_t)NN * D * 4); // NE int2 = 5 MB (8B-aligned)
    int*   ints  = (int*)(edata + NE);
    int*   deg    = ints;            // NN
    int*   starts = deg + NN;        // NN+1
    int*   fillc  = starts + NN + 1; // NN
    int*   blksum = fillc + NN;      // 256

    zero_counters<<<(NN + 255) / 256, 256, 0, stream>>>(deg, fillc);
    count_deg<<<(NE + 255) / 256, 256, 0, stream>>>(dst, deg);
    scan1<<<NBLK, 256, 0, stream>>>(deg, starts, blksum);
    scan2<<<1, 256, 0, stream>>>(blksum);
    scan3<<<NBLK, 256, 0, stream>>>(blksum, starts);
    fill_csr<<<(NE + 255) / 256, 256, 0, stream>>>(src, dst, ew, starts, fillc, edata);
    aggregate<<<(NN + 3) / 4, 256, 0, stream>>>(x, starts, edata, agg);
    gemm_bias_relu<<<(NN + BN - 1) / BN, 256, 0, stream>>>(agg, W, bias, out);
}

// Round 3
// 154.486 us; speedup vs baseline: 7.2916x; 1.2730x over previous
//
#include <hip/hip_runtime.h>

#define NN 50000
#define NE 625000
#define D  128
#define NBLK 196   // ceil(NN/256)
#define GBM 128    // GEMM rows per block

typedef __attribute__((ext_vector_type(8))) short bf16x8;
typedef __attribute__((ext_vector_type(4))) float f32x4;

// ---------------- CSR build ----------------

__global__ __launch_bounds__(256) void zero_counters(int* __restrict__ deg,
                                                     int* __restrict__ fillc) {
    int i = blockIdx.x * blockDim.x + threadIdx.x;
    if (i < NN) { deg[i] = 0; fillc[i] = 0; }
}

__global__ __launch_bounds__(256) void count_deg(const int* __restrict__ dst,
                                                 int* __restrict__ deg) {
    int e = blockIdx.x * blockDim.x + threadIdx.x;
    if (e < NE) atomicAdd(&deg[dst[e]], 1);
}

__global__ __launch_bounds__(256) void scan1(const int* __restrict__ deg,
                                             int* __restrict__ starts,
                                             int* __restrict__ blksum) {
    __shared__ int tmp[256];
    int tid = threadIdx.x;
    int gid = blockIdx.x * 256 + tid;
    int v = (gid < NN) ? deg[gid] : 0;
    tmp[tid] = v; __syncthreads();
#pragma unroll
    for (int off = 1; off < 256; off <<= 1) {
        int t = (tid >= off) ? tmp[tid - off] : 0;
        __syncthreads();
        tmp[tid] += t;
        __syncthreads();
    }
    if (gid < NN) starts[gid] = tmp[tid] - v;
    if (tid == 255) blksum[blockIdx.x] = tmp[255];
}

__global__ __launch_bounds__(256) void scan2(int* __restrict__ blksum) {
    __shared__ int tmp[256];
    int tid = threadIdx.x;
    int v = (tid < NBLK) ? blksum[tid] : 0;
    tmp[tid] = v; __syncthreads();
#pragma unroll
    for (int off = 1; off < 256; off <<= 1) {
        int t = (tid >= off) ? tmp[tid - off] : 0;
        __syncthreads();
        tmp[tid] += t;
        __syncthreads();
    }
    blksum[tid] = tmp[tid] - v;
}

__global__ __launch_bounds__(256) void scan3(const int* __restrict__ blksum,
                                             int* __restrict__ starts) {
    int gid = blockIdx.x * 256 + threadIdx.x;
    if (gid < NN) starts[gid] += blksum[blockIdx.x];
    if (gid == 0) starts[NN] = NE;
}

__global__ __launch_bounds__(256) void fill_csr(const int* __restrict__ src,
                                                const int* __restrict__ dst,
                                                const float* __restrict__ ew,
                                                const int* __restrict__ starts,
                                                int* __restrict__ fillc,
                                                int2* __restrict__ edata) {
    int e = blockIdx.x * blockDim.x + threadIdx.x;
    if (e >= NE) return;
    int d = dst[e];
    int p = atomicAdd(&fillc[d], 1);
    edata[starts[d] + p] = make_int2(src[e], __float_as_int(ew[e]));
}

// ---------------- aggregate (gather) ----------------
__global__ __launch_bounds__(256) void aggregate(const float* __restrict__ x,
                                                 const int* __restrict__ starts,
                                                 const int2* __restrict__ edata,
                                                 float* __restrict__ agg) {
    int node = blockIdx.x * 4 + (threadIdx.x >> 6);
    int t    = threadIdx.x & 63;
    if (node >= NN) return;
    const float2* x2 = reinterpret_cast<const float2*>(x);
    int b = starts[node];
    int e = starts[node + 1];
    float2 acc{0.f, 0.f};
    int i = b;
    for (; i + 1 < e; i += 2) {
        int2 e0 = edata[i], e1 = edata[i + 1];
        float  w0 = __int_as_float(e0.y), w1 = __int_as_float(e1.y);
        float2 v0 = x2[(size_t)e0.x * 64 + t];
        float2 v1 = x2[(size_t)e1.x * 64 + t];
        acc.x += v0.x * w0; acc.y += v0.y * w0;
        acc.x += v1.x * w1; acc.y += v1.y * w1;
    }
    if (i < e) {
        int2 e0 = edata[i];
        float  w0 = __int_as_float(e0.y);
        float2 v0 = x2[(size_t)e0.x * 64 + t];
        acc.x += v0.x * w0; acc.y += v0.y * w0;
    }
    reinterpret_cast<float2*>(agg)[(size_t)node * 64 + t] = acc;
}

// ---------------- W split (fp32 -> bf16 hi/lo, pre-swizzled) ----------------
// hi in low 16 of packed word = element 2w; high 16 = element 2w+1
__device__ inline unsigned pack_hi(float a, float b, float& ra, float& rb) {
    unsigned ba = __float_as_uint(a) & 0xffff0000u;
    unsigned bb = __float_as_uint(b) & 0xffff0000u;
    ra = a - __uint_as_float(ba);
    rb = b - __uint_as_float(bb);
    return (ba >> 16) | bb;
}
__device__ inline unsigned pack_lo(float ra, float rb) {
    return (__float_as_uint(ra) >> 16) | (__float_as_uint(rb) & 0xffff0000u);
}

// one thread per 8-element chunk: 128 cols x 16 chunks = 2048 threads
__global__ __launch_bounds__(256) void split_w(const float* __restrict__ W,
                                               ushort* __restrict__ wsp) {
    int g = blockIdx.x * 256 + threadIdx.x;
    if (g >= 128 * 16) return;
    int col = g >> 4;
    int c16 = g & 15;
    const float4* wp = (const float4*)(W + (size_t)col * D + c16 * 8);
    float4 v0 = wp[0], v1 = wp[1];
    float r0, r1, r2, r3, r4, r5, r6, r7;
    uint4 hi, lo;
    hi.x = pack_hi(v0.x, v0.y, r0, r1);
    hi.y = pack_hi(v0.z, v0.w, r2, r3);
    hi.z = pack_hi(v1.x, v1.y, r4, r5);
    hi.w = pack_hi(v1.z, v1.w, r6, r7);
    lo.x = pack_lo(r0, r1); lo.y = pack_lo(r2, r3);
    lo.z = pack_lo(r4, r5); lo.w = pack_lo(r6, r7);
    int sidx = col * 16 + (c16 ^ (col & 15));   // XOR swizzle (bank-conflict-free reads)
    ((uint4*)wsp)[sidx] = hi;                   // whi region
    ((uint4*)(wsp + 16384))[sidx] = lo;         // wlo region
}

// ---------------- GEMM via bf16 MFMA, 3-term split precision ----------------
// out[n][o] = relu(sum_k agg[n][k]*W[o][k] + bias[o])
// block = 256 thr = 4 waves; each wave: 32 rows x 128 cols, K=128 unrolled
__global__ __launch_bounds__(256) void gemm_mfma(const float* __restrict__ agg,
                                                 const ushort* __restrict__ wsp,
                                                 const float* __restrict__ bias,
                                                 float* __restrict__ out) {
    __shared__ ushort wl[32768];   // whi [0,16384), wlo [16384,32768) — 64 KB
    const int tid = threadIdx.x;

    // stage pre-swizzled Wsplit linearly: 4096 x 16B
    {
        const uint4* s = (const uint4*)wsp;
        uint4* d = (uint4*)wl;
#pragma unroll
        for (int i = 0; i < 16; ++i)
            d[i * 256 + tid] = s[i * 256 + tid];
    }
    __syncthreads();

    const int wid = tid >> 6, lane = tid & 63;
    const int l15 = lane & 15, kg = lane >> 4;
    const int wrbase = blockIdx.x * GBM + wid * 32;

    f32x4 acc[2][8];
    const f32x4 fz = {0.f, 0.f, 0.f, 0.f};
#pragma unroll
    for (int m = 0; m < 2; ++m)
#pragma unroll
        for (int n = 0; n < 8; ++n) acc[m][n] = fz;

    int arow0 = wrbase + l15;
    int arow1 = wrbase + 16 + l15;
    const float* a0p = agg + (size_t)(arow0 < NN ? arow0 : NN - 1) * D + kg * 8;
    const float* a1p = agg + (size_t)(arow1 < NN ? arow1 : NN - 1) * D + kg * 8;

#pragma unroll
    for (int kk = 0; kk < 4; ++kk) {
        float4 u0 = *(const float4*)(a0p + kk * 32);
        float4 u1 = *(const float4*)(a0p + kk * 32 + 4);
        float4 v0 = *(const float4*)(a1p + kk * 32);
        float4 v1 = *(const float4*)(a1p + kk * 32 + 4);
        float r0, r1, r2, r3, r4, r5, r6, r7;
        uint4 h0, l0, h1, l1;
        h0.x = pack_hi(u0.x, u0.y, r0, r1);
        h0.y = pack_hi(u0.z, u0.w, r2, r3);
        h0.z = pack_hi(u1.x, u1.y, r4, r5);
        h0.w = pack_hi(u1.z, u1.w, r6, r7);
        l0.x = pack_lo(r0, r1); l0.y = pack_lo(r2, r3);
        l0.z = pack_lo(r4, r5); l0.w = pack_lo(r6, r7);
        h1.x = pack_hi(v0.x, v0.y, r0, r1);
        h1.y = pack_hi(v0.z, v0.w, r2, r3);
        h1.z = pack_hi(v1.x, v1.y, r4, r5);
        h1.w = pack_hi(v1.z, v1.w, r6, r7);
        l1.x = pack_lo(r0, r1); l1.y = pack_lo(r2, r3);
        l1.z = pack_lo(r4, r5); l1.w = pack_lo(r6, r7);
        bf16x8 a0hi = *(bf16x8*)&h0;
        bf16x8 a0lo = *(bf16x8*)&l0;
        bf16x8 a1hi = *(bf16x8*)&h1;
        bf16x8 a1lo = *(bf16x8*)&l1;

        int coff = ((kk * 4 + kg) ^ l15) * 8;   // swizzled chunk offset (ushorts)
#pragma unroll
        for (int nf = 0; nf < 8; ++nf) {
            int bidx = (16 * nf + l15) * 128 + coff;
            bf16x8 bhi = *(const bf16x8*)&wl[bidx];
            bf16x8 blo = *(const bf16x8*)&wl[16384 + bidx];
            acc[0][nf] = __builtin_amdgcn_mfma_f32_16x16x32_bf16(a0hi, bhi, acc[0][nf], 0, 0, 0);
            acc[1][nf] = __builtin_amdgcn_mfma_f32_16x16x32_bf16(a1hi, bhi, acc[1][nf], 0, 0, 0);
            acc[0][nf] = __builtin_amdgcn_mfma_f32_16x16x32_bf16(a0lo, bhi, acc[0][nf], 0, 0, 0);
            acc[1][nf] = __builtin_amdgcn_mfma_f32_16x16x32_bf16(a1lo, bhi, acc[1][nf], 0, 0, 0);
            acc[0][nf] = __builtin_amdgcn_mfma_f32_16x16x32_bf16(a0hi, blo, acc[0][nf], 0, 0, 0);
            acc[1][nf] = __builtin_amdgcn_mfma_f32_16x16x32_bf16(a1hi, blo, acc[1][nf], 0, 0, 0);
        }
    }

    const int rofs = kg * 4;
#pragma unroll
    for (int nf = 0; nf < 8; ++nf) {
        int col = 16 * nf + l15;
        float bv = bias[col];
#pragma unroll
        for (int m = 0; m < 2; ++m) {
#pragma unroll
            for (int r = 0; r < 4; ++r) {
                int row = wrbase + 16 * m + rofs + r;
                if (row < NN) {
                    float h = acc[m][nf][r] + bv;
                    out[(size_t)row * D + col] = h > 0.f ? h : 0.f;
                }
            }
        }
    }
}

extern "C" void kernel_launch(void* const* d_in, const int* in_sizes, int n_in,
                              void* d_out, int out_size, void* d_ws, size_t ws_size,
                              hipStream_t stream) {
    const float* x    = (const float*)d_in[0];
    const int*   eidx = (const int*)d_in[1];   // [2, E] flat: src then dst
    const float* ew   = (const float*)d_in[2];
    const float* W    = (const float*)d_in[3];
    const float* bias = (const float*)d_in[4];
    float* out = (float*)d_out;

    const int* src = eidx;
    const int* dst = eidx + NE;

    // workspace layout
    char* base = (char*)d_ws;
    float* agg   = (float*)base;                       // NN*D floats = 25.6 MB
    int2*  edata = (int2*)(base + (size_t)NN * D * 4); // NE int2 = 5 MB
    int*   ints  = (int*)(edata + NE);
    int*   deg    = ints;            // NN
    int*   starts = deg + NN;        // NN+1
    int*   fillc  = starts + NN + 1; // NN
    int*   blksum = fillc + NN;      // 256
    ushort* wsp = (ushort*)((((uintptr_t)(blksum + 256)) + 15) & ~(uintptr_t)15); // 64 KB

    split_w<<<8, 256, 0, stream>>>(W, wsp);
    zero_counters<<<(NN + 255) / 256, 256, 0, stream>>>(deg, fillc);
    count_deg<<<(NE + 255) / 256, 256, 0, stream>>>(dst, deg);
    scan1<<<NBLK, 256, 0, stream>>>(deg, starts, blksum);
    scan2<<<1, 256, 0, stream>>>(blksum);
    scan3<<<NBLK, 256, 0, stream>>>(blksum, starts);
    fill_csr<<<(NE + 255) / 256, 256, 0, stream>>>(src, dst, ew, starts, fillc, edata);
    aggregate<<<(NN + 3) / 4, 256, 0, stream>>>(x, starts, edata, agg);
    gemm_mfma<<<(NN + GBM - 1) / GBM, 256, 0, stream>>>(agg, wsp, bias, out);
}

// Round 4
// 142.903 us; speedup vs baseline: 7.8826x; 1.0811x over previous
//
#include <hip/hip_runtime.h>

#define NN 50000
#define NE 625000
#define D  128
#define NBLK 196   // ceil(NN/256)
#define GBM 128    // GEMM rows per block

typedef __attribute__((ext_vector_type(8))) short bf16x8;
typedef __attribute__((ext_vector_type(4))) float f32x4;

// ---------------- prep: zero counters + convert x -> bf16 ----------------

__device__ inline unsigned f2bf_rne(float f) {
    unsigned u = __float_as_uint(f);
    u += 0x7FFFu + ((u >> 16) & 1u);   // round-to-nearest-even
    return u >> 16;
}

// grid 3125 x 256 = 800000 threads; thread g converts x[8g..8g+8), g<NN zeroes counters
__global__ __launch_bounds__(256) void prep(const float* __restrict__ x,
                                            unsigned* __restrict__ xb,  // as uint pairs
                                            int* __restrict__ deg,
                                            int* __restrict__ fillc) {
    int g = blockIdx.x * 256 + threadIdx.x;
    if (g < NN) { deg[g] = 0; fillc[g] = 0; }
    if (g >= NN * D / 8) return;
    const float4* xp = (const float4*)(x + (size_t)g * 8);
    float4 a = xp[0], b = xp[1];
    uint4 o;
    o.x = f2bf_rne(a.x) | (f2bf_rne(a.y) << 16);
    o.y = f2bf_rne(a.z) | (f2bf_rne(a.w) << 16);
    o.z = f2bf_rne(b.x) | (f2bf_rne(b.y) << 16);
    o.w = f2bf_rne(b.z) | (f2bf_rne(b.w) << 16);
    ((uint4*)xb)[g / 4 * 4 + (g & 3)] = o;   // == ((uint4*)xb)[g]
}

// ---------------- CSR build ----------------

__global__ __launch_bounds__(256) void count_deg(const int* __restrict__ dst,
                                                 int* __restrict__ deg) {
    int e = blockIdx.x * blockDim.x + threadIdx.x;
    if (e < NE) atomicAdd(&deg[dst[e]], 1);
}

__global__ __launch_bounds__(256) void scan1(const int* __restrict__ deg,
                                             int* __restrict__ starts,
                                             int* __restrict__ blksum) {
    __shared__ int tmp[256];
    int tid = threadIdx.x;
    int gid = blockIdx.x * 256 + tid;
    int v = (gid < NN) ? deg[gid] : 0;
    tmp[tid] = v; __syncthreads();
#pragma unroll
    for (int off = 1; off < 256; off <<= 1) {
        int t = (tid >= off) ? tmp[tid - off] : 0;
        __syncthreads();
        tmp[tid] += t;
        __syncthreads();
    }
    if (gid < NN) starts[gid] = tmp[tid] - v;
    if (tid == 255) blksum[blockIdx.x] = tmp[255];
}

__global__ __launch_bounds__(256) void scan2(int* __restrict__ blksum) {
    __shared__ int tmp[256];
    int tid = threadIdx.x;
    int v = (tid < NBLK) ? blksum[tid] : 0;
    tmp[tid] = v; __syncthreads();
#pragma unroll
    for (int off = 1; off < 256; off <<= 1) {
        int t = (tid >= off) ? tmp[tid - off] : 0;
        __syncthreads();
        tmp[tid] += t;
        __syncthreads();
    }
    blksum[tid] = tmp[tid] - v;
}

__global__ __launch_bounds__(256) void scan3(const int* __restrict__ blksum,
                                             int* __restrict__ starts) {
    int gid = blockIdx.x * 256 + threadIdx.x;
    if (gid < NN) starts[gid] += blksum[blockIdx.x];
    if (gid == 0) starts[NN] = NE;
}

__global__ __launch_bounds__(256) void fill_csr(const int* __restrict__ src,
                                                const int* __restrict__ dst,
                                                const float* __restrict__ ew,
                                                const int* __restrict__ starts,
                                                int* __restrict__ fillc,
                                                int2* __restrict__ edata) {
    int e = blockIdx.x * blockDim.x + threadIdx.x;
    if (e >= NE) return;
    int d = dst[e];
    int p = atomicAdd(&fillc[d], 1);
    edata[starts[d] + p] = make_int2(src[e], __float_as_int(ew[e]));
}

// ---------------- aggregate (gather, bf16 x) ----------------
// one 64-lane wave per node; lane t owns dims {2t, 2t+1} (one uint = 2 bf16)
__global__ __launch_bounds__(256) void aggregate(const unsigned* __restrict__ xb,
                                                 const int* __restrict__ starts,
                                                 const int2* __restrict__ edata,
                                                 float* __restrict__ agg) {
    int node = blockIdx.x * 4 + (threadIdx.x >> 6);
    int t    = threadIdx.x & 63;
    if (node >= NN) return;
    int b = starts[node];
    int e = starts[node + 1];
    float2 acc{0.f, 0.f};
    int i = b;
    for (; i + 3 < e; i += 4) {
        int2 e0 = edata[i], e1 = edata[i + 1], e2 = edata[i + 2], e3 = edata[i + 3];
        unsigned u0 = xb[(size_t)e0.x * 64 + t];
        unsigned u1 = xb[(size_t)e1.x * 64 + t];
        unsigned u2 = xb[(size_t)e2.x * 64 + t];
        unsigned u3 = xb[(size_t)e3.x * 64 + t];
        float w0 = __int_as_float(e0.y), w1 = __int_as_float(e1.y);
        float w2 = __int_as_float(e2.y), w3 = __int_as_float(e3.y);
        acc.x += __uint_as_float(u0 << 16) * w0;
        acc.y += __uint_as_float(u0 & 0xffff0000u) * w0;
        acc.x += __uint_as_float(u1 << 16) * w1;
        acc.y += __uint_as_float(u1 & 0xffff0000u) * w1;
        acc.x += __uint_as_float(u2 << 16) * w2;
        acc.y += __uint_as_float(u2 & 0xffff0000u) * w2;
        acc.x += __uint_as_float(u3 << 16) * w3;
        acc.y += __uint_as_float(u3 & 0xffff0000u) * w3;
    }
    for (; i < e; ++i) {
        int2 e0 = edata[i];
        unsigned u0 = xb[(size_t)e0.x * 64 + t];
        float w0 = __int_as_float(e0.y);
        acc.x += __uint_as_float(u0 << 16) * w0;
        acc.y += __uint_as_float(u0 & 0xffff0000u) * w0;
    }
    reinterpret_cast<float2*>(agg)[(size_t)node * 64 + t] = acc;
}

// ---------------- W split (fp32 -> bf16 hi/lo, pre-swizzled) ----------------
__device__ inline unsigned pack_hi(float a, float b, float& ra, float& rb) {
    unsigned ba = __float_as_uint(a) & 0xffff0000u;
    unsigned bb = __float_as_uint(b) & 0xffff0000u;
    ra = a - __uint_as_float(ba);
    rb = b - __uint_as_float(bb);
    return (ba >> 16) | bb;
}
__device__ inline unsigned pack_lo(float ra, float rb) {
    return (__float_as_uint(ra) >> 16) | (__float_as_uint(rb) & 0xffff0000u);
}

__global__ __launch_bounds__(256) void split_w(const float* __restrict__ W,
                                               ushort* __restrict__ wsp) {
    int g = blockIdx.x * 256 + threadIdx.x;
    if (g >= 128 * 16) return;
    int col = g >> 4;
    int c16 = g & 15;
    const float4* wp = (const float4*)(W + (size_t)col * D + c16 * 8);
    float4 v0 = wp[0], v1 = wp[1];
    float r0, r1, r2, r3, r4, r5, r6, r7;
    uint4 hi, lo;
    hi.x = pack_hi(v0.x, v0.y, r0, r1);
    hi.y = pack_hi(v0.z, v0.w, r2, r3);
    hi.z = pack_hi(v1.x, v1.y, r4, r5);
    hi.w = pack_hi(v1.z, v1.w, r6, r7);
    lo.x = pack_lo(r0, r1); lo.y = pack_lo(r2, r3);
    lo.z = pack_lo(r4, r5); lo.w = pack_lo(r6, r7);
    int sidx = col * 16 + (c16 ^ (col & 15));
    ((uint4*)wsp)[sidx] = hi;
    ((uint4*)(wsp + 16384))[sidx] = lo;
}

// ---------------- GEMM via bf16 MFMA, 3-term split precision ----------------
__global__ __launch_bounds__(256) void gemm_mfma(const float* __restrict__ agg,
                                                 const ushort* __restrict__ wsp,
                                                 const float* __restrict__ bias,
                                                 float* __restrict__ out) {
    __shared__ ushort wl[32768];
    const int tid = threadIdx.x;
    {
        const uint4* s = (const uint4*)wsp;
        uint4* d = (uint4*)wl;
#pragma unroll
        for (int i = 0; i < 16; ++i)
            d[i * 256 + tid] = s[i * 256 + tid];
    }
    __syncthreads();

    const int wid = tid >> 6, lane = tid & 63;
    const int l15 = lane & 15, kg = lane >> 4;
    const int wrbase = blockIdx.x * GBM + wid * 32;

    f32x4 acc[2][8];
    const f32x4 fz = {0.f, 0.f, 0.f, 0.f};
#pragma unroll
    for (int m = 0; m < 2; ++m)
#pragma unroll
        for (int n = 0; n < 8; ++n) acc[m][n] = fz;

    int arow0 = wrbase + l15;
    int arow1 = wrbase + 16 + l15;
    const float* a0p = agg + (size_t)(arow0 < NN ? arow0 : NN - 1) * D + kg * 8;
    const float* a1p = agg + (size_t)(arow1 < NN ? arow1 : NN - 1) * D + kg * 8;

#pragma unroll
    for (int kk = 0; kk < 4; ++kk) {
        float4 u0 = *(const float4*)(a0p + kk * 32);
        float4 u1 = *(const float4*)(a0p + kk * 32 + 4);
        float4 v0 = *(const float4*)(a1p + kk * 32);
        float4 v1 = *(const float4*)(a1p + kk * 32 + 4);
        float r0, r1, r2, r3, r4, r5, r6, r7;
        uint4 h0, l0, h1, l1;
        h0.x = pack_hi(u0.x, u0.y, r0, r1);
        h0.y = pack_hi(u0.z, u0.w, r2, r3);
        h0.z = pack_hi(u1.x, u1.y, r4, r5);
        h0.w = pack_hi(u1.z, u1.w, r6, r7);
        l0.x = pack_lo(r0, r1); l0.y = pack_lo(r2, r3);
        l0.z = pack_lo(r4, r5); l0.w = pack_lo(r6, r7);
        h1.x = pack_hi(v0.x, v0.y, r0, r1);
        h1.y = pack_hi(v0.z, v0.w, r2, r3);
        h1.z = pack_hi(v1.x, v1.y, r4, r5);
        h1.w = pack_hi(v1.z, v1.w, r6, r7);
        l1.x = pack_lo(r0, r1); l1.y = pack_lo(r2, r3);
        l1.z = pack_lo(r4, r5); l1.w = pack_lo(r6, r7);
        bf16x8 a0hi = *(bf16x8*)&h0;
        bf16x8 a0lo = *(bf16x8*)&l0;
        bf16x8 a1hi = *(bf16x8*)&h1;
        bf16x8 a1lo = *(bf16x8*)&l1;

        int coff = ((kk * 4 + kg) ^ l15) * 8;
#pragma unroll
        for (int nf = 0; nf < 8; ++nf) {
            int bidx = (16 * nf + l15) * 128 + coff;
            bf16x8 bhi = *(const bf16x8*)&wl[bidx];
            bf16x8 blo = *(const bf16x8*)&wl[16384 + bidx];
            acc[0][nf] = __builtin_amdgcn_mfma_f32_16x16x32_bf16(a0hi, bhi, acc[0][nf], 0, 0, 0);
            acc[1][nf] = __builtin_amdgcn_mfma_f32_16x16x32_bf16(a1hi, bhi, acc[1][nf], 0, 0, 0);
            acc[0][nf] = __builtin_amdgcn_mfma_f32_16x16x32_bf16(a0lo, bhi, acc[0][nf], 0, 0, 0);
            acc[1][nf] = __builtin_amdgcn_mfma_f32_16x16x32_bf16(a1lo, bhi, acc[1][nf], 0, 0, 0);
            acc[0][nf] = __builtin_amdgcn_mfma_f32_16x16x32_bf16(a0hi, blo, acc[0][nf], 0, 0, 0);
            acc[1][nf] = __builtin_amdgcn_mfma_f32_16x16x32_bf16(a1hi, blo, acc[1][nf], 0, 0, 0);
        }
    }

    const int rofs = kg * 4;
#pragma unroll
    for (int nf = 0; nf < 8; ++nf) {
        int col = 16 * nf + l15;
        float bv = bias[col];
#pragma unroll
        for (int m = 0; m < 2; ++m) {
#pragma unroll
            for (int r = 0; r < 4; ++r) {
                int row = wrbase + 16 * m + rofs + r;
                if (row < NN) {
                    float h = acc[m][nf][r] + bv;
                    out[(size_t)row * D + col] = h > 0.f ? h : 0.f;
                }
            }
        }
    }
}

extern "C" void kernel_launch(void* const* d_in, const int* in_sizes, int n_in,
                              void* d_out, int out_size, void* d_ws, size_t ws_size,
                              hipStream_t stream) {
    const float* x    = (const float*)d_in[0];
    const int*   eidx = (const int*)d_in[1];   // [2, E] flat: src then dst
    const float* ew   = (const float*)d_in[2];
    const float* W    = (const float*)d_in[3];
    const float* bias = (const float*)d_in[4];
    float* out = (float*)d_out;

    const int* src = eidx;
    const int* dst = eidx + NE;

    // workspace layout
    char* base = (char*)d_ws;
    float* agg   = (float*)base;                       // NN*D fp32 = 25.6 MB
    int2*  edata = (int2*)(base + (size_t)NN * D * 4); // NE int2 = 5 MB
    int*   ints  = (int*)(edata + NE);
    int*   deg    = ints;            // NN
    int*   starts = deg + NN;        // NN+1
    int*   fillc  = starts + NN + 1; // NN
    int*   blksum = fillc + NN;      // 256
    ushort* wsp = (ushort*)((((uintptr_t)(blksum + 256)) + 15) & ~(uintptr_t)15); // 64 KB
    unsigned* xb = (unsigned*)(wsp + 32768);           // NN*D bf16 = 12.8 MB

    split_w<<<8, 256, 0, stream>>>(W, wsp);
    prep<<<3125, 256, 0, stream>>>(x, xb, deg, fillc);
    count_deg<<<(NE + 255) / 256, 256, 0, stream>>>(dst, deg);
    scan1<<<NBLK, 256, 0, stream>>>(deg, starts, blksum);
    scan2<<<1, 256, 0, stream>>>(blksum);
    scan3<<<NBLK, 256, 0, stream>>>(blksum, starts);
    fill_csr<<<(NE + 255) / 256, 256, 0, stream>>>(src, dst, ew, starts, fillc, edata);
    aggregate<<<(NN + 3) / 4, 256, 0, stream>>>(xb, starts, edata, agg);
    gemm_mfma<<<(NN + GBM - 1) / GBM, 256, 0, stream>>>(agg, wsp, bias, out);
}

// Round 5
// 102.316 us; speedup vs baseline: 11.0095x; 1.3967x over previous
//
#include <hip/hip_runtime.h>
#include <hip/hip_fp16.h>

#define NN 50000
#define NE 625000
#define D  128
#define CAP 64      // bucket capacity per node (avg degree 12.5; P(>64) ~ 1e-30)
#define GBM 128     // GEMM rows per block
#define PREP_BLKS 3125   // NN*D/8/256

typedef __attribute__((ext_vector_type(8))) short bf16x8;
typedef __attribute__((ext_vector_type(4))) float f32x4;

__device__ inline unsigned f2bf_rne(float f) {
    unsigned u = __float_as_uint(f);
    u += 0x7FFFu + ((u >> 16) & 1u);
    return u >> 16;
}

// ---- W split helpers (fp32 -> bf16 hi + residual lo), pre-swizzled ----
__device__ inline unsigned pack_hi(float a, float b, float& ra, float& rb) {
    unsigned ba = __float_as_uint(a) & 0xffff0000u;
    unsigned bb = __float_as_uint(b) & 0xffff0000u;
    ra = a - __uint_as_float(ba);
    rb = b - __uint_as_float(bb);
    return (ba >> 16) | bb;
}
__device__ inline unsigned pack_lo(float ra, float rb) {
    return (__float_as_uint(ra) >> 16) | (__float_as_uint(rb) & 0xffff0000u);
}

// prep: zero fillc/ovf_cnt + convert x -> bf16 + (blocks >= PREP_BLKS) split W
__global__ __launch_bounds__(256) void prep(const float* __restrict__ x,
                                            const float* __restrict__ W,
                                            unsigned* __restrict__ xb,
                                            ushort* __restrict__ wsp,
                                            int* __restrict__ fillc,
                                            int* __restrict__ ovf_cnt) {
    if (blockIdx.x >= PREP_BLKS) {
        int g = (blockIdx.x - PREP_BLKS) * 256 + threadIdx.x;
        if (g >= 128 * 16) return;
        int col = g >> 4;
        int c16 = g & 15;
        const float4* wp = (const float4*)(W + (size_t)col * D + c16 * 8);
        float4 v0 = wp[0], v1 = wp[1];
        float r0, r1, r2, r3, r4, r5, r6, r7;
        uint4 hi, lo;
        hi.x = pack_hi(v0.x, v0.y, r0, r1);
        hi.y = pack_hi(v0.z, v0.w, r2, r3);
        hi.z = pack_hi(v1.x, v1.y, r4, r5);
        hi.w = pack_hi(v1.z, v1.w, r6, r7);
        lo.x = pack_lo(r0, r1); lo.y = pack_lo(r2, r3);
        lo.z = pack_lo(r4, r5); lo.w = pack_lo(r6, r7);
        int sidx = col * 16 + (c16 ^ (col & 15));
        ((uint4*)wsp)[sidx] = hi;
        ((uint4*)(wsp + 16384))[sidx] = lo;
        return;
    }
    int g = blockIdx.x * 256 + threadIdx.x;
    if (g < NN) fillc[g] = 0;
    if (g == 0) *ovf_cnt = 0;
    const float4* xp = (const float4*)(x + (size_t)g * 8);
    float4 a = xp[0], b = xp[1];
    uint4 o;
    o.x = f2bf_rne(a.x) | (f2bf_rne(a.y) << 16);
    o.y = f2bf_rne(a.z) | (f2bf_rne(a.w) << 16);
    o.z = f2bf_rne(b.x) | (f2bf_rne(b.y) << 16);
    o.w = f2bf_rne(b.z) | (f2bf_rne(b.w) << 16);
    ((uint4*)xb)[g] = o;
}

// ---- bucket fill: entry = (src:16 | fp16(weight):16), slot via one atomic ----
__global__ __launch_bounds__(256) void fill_bucket(const int* __restrict__ src,
                                                   const int* __restrict__ dst,
                                                   const float* __restrict__ ew,
                                                   int* __restrict__ fillc,
                                                   unsigned* __restrict__ buck,
                                                   int* __restrict__ ovf_cnt,
                                                   uint2* __restrict__ ovf) {
    int e = blockIdx.x * blockDim.x + threadIdx.x;
    if (e >= NE) return;
    int d = dst[e];
    unsigned entry = ((unsigned)src[e] << 16) |
                     (unsigned)__half_as_ushort(__float2half(ew[e]));
    int p = atomicAdd(&fillc[d], 1);
    if (p < CAP) {
        buck[(size_t)d * CAP + p] = entry;
    } else {
        int o = atomicAdd(ovf_cnt, 1);
        ovf[o] = make_uint2((unsigned)d, entry);
    }
}

// ---- aggregate (gather, bf16 x, 4B entries) ----
// one 64-lane wave per node; lane t owns dims {2t, 2t+1}
__global__ __launch_bounds__(256) void aggregate(const unsigned* __restrict__ xb,
                                                 const int* __restrict__ fillc,
                                                 const unsigned* __restrict__ buck,
                                                 float* __restrict__ agg) {
    int node = blockIdx.x * 4 + (threadIdx.x >> 6);
    int t    = threadIdx.x & 63;
    if (node >= NN) return;
    int cnt = fillc[node];
    if (cnt > CAP) cnt = CAP;
    const unsigned* bp = buck + (size_t)node * CAP;
    float2 acc{0.f, 0.f};
    int i = 0;
    for (; i + 3 < cnt; i += 4) {
        unsigned q0 = bp[i], q1 = bp[i + 1], q2 = bp[i + 2], q3 = bp[i + 3];
        unsigned u0 = xb[(size_t)(q0 >> 16) * 64 + t];
        unsigned u1 = xb[(size_t)(q1 >> 16) * 64 + t];
        unsigned u2 = xb[(size_t)(q2 >> 16) * 64 + t];
        unsigned u3 = xb[(size_t)(q3 >> 16) * 64 + t];
        float w0 = __half2float(__ushort_as_half((ushort)(q0 & 0xffffu)));
        float w1 = __half2float(__ushort_as_half((ushort)(q1 & 0xffffu)));
        float w2 = __half2float(__ushort_as_half((ushort)(q2 & 0xffffu)));
        float w3 = __half2float(__ushort_as_half((ushort)(q3 & 0xffffu)));
        acc.x += __uint_as_float(u0 << 16) * w0;
        acc.y += __uint_as_float(u0 & 0xffff0000u) * w0;
        acc.x += __uint_as_float(u1 << 16) * w1;
        acc.y += __uint_as_float(u1 & 0xffff0000u) * w1;
        acc.x += __uint_as_float(u2 << 16) * w2;
        acc.y += __uint_as_float(u2 & 0xffff0000u) * w2;
        acc.x += __uint_as_float(u3 << 16) * w3;
        acc.y += __uint_as_float(u3 & 0xffff0000u) * w3;
    }
    for (; i < cnt; ++i) {
        unsigned q0 = bp[i];
        unsigned u0 = xb[(size_t)(q0 >> 16) * 64 + t];
        float w0 = __half2float(__ushort_as_half((ushort)(q0 & 0xffffu)));
        acc.x += __uint_as_float(u0 << 16) * w0;
        acc.y += __uint_as_float(u0 & 0xffff0000u) * w0;
    }
    reinterpret_cast<float2*>(agg)[(size_t)node * 64 + t] = acc;
}

// ---- overflow fixup (never triggers for this dataset; correctness net) ----
__global__ __launch_bounds__(256) void ovf_fix(const unsigned* __restrict__ xb,
                                               const int* __restrict__ ovf_cnt,
                                               const uint2* __restrict__ ovf,
                                               float* __restrict__ agg) {
    int n = *ovf_cnt;
    int widx = (blockIdx.x * 256 + threadIdx.x) >> 6;
    int t = threadIdx.x & 63;
    int nw = gridDim.x * 4;
    for (int o = widx; o < n; o += nw) {
        unsigned d = ovf[o].x;
        unsigned q = ovf[o].y;
        unsigned u = xb[(size_t)(q >> 16) * 64 + t];
        float w = __half2float(__ushort_as_half((ushort)(q & 0xffffu)));
        atomicAdd(&agg[(size_t)d * D + 2 * t],     __uint_as_float(u << 16) * w);
        atomicAdd(&agg[(size_t)d * D + 2 * t + 1], __uint_as_float(u & 0xffff0000u) * w);
    }
}

// ---- GEMM via bf16 MFMA, 3-term split precision ----
__global__ __launch_bounds__(256) void gemm_mfma(const float* __restrict__ agg,
                                                 const ushort* __restrict__ wsp,
                                                 const float* __restrict__ bias,
                                                 float* __restrict__ out) {
    __shared__ ushort wl[32768];
    const int tid = threadIdx.x;
    {
        const uint4* s = (const uint4*)wsp;
        uint4* d = (uint4*)wl;
#pragma unroll
        for (int i = 0; i < 16; ++i)
            d[i * 256 + tid] = s[i * 256 + tid];
    }
    __syncthreads();

    const int wid = tid >> 6, lane = tid & 63;
    const int l15 = lane & 15, kg = lane >> 4;
    const int wrbase = blockIdx.x * GBM + wid * 32;

    f32x4 acc[2][8];
    const f32x4 fz = {0.f, 0.f, 0.f, 0.f};
#pragma unroll
    for (int m = 0; m < 2; ++m)
#pragma unroll
        for (int n = 0; n < 8; ++n) acc[m][n] = fz;

    int arow0 = wrbase + l15;
    int arow1 = wrbase + 16 + l15;
    const float* a0p = agg + (size_t)(arow0 < NN ? arow0 : NN - 1) * D + kg * 8;
    const float* a1p = agg + (size_t)(arow1 < NN ? arow1 : NN - 1) * D + kg * 8;

#pragma unroll
    for (int kk = 0; kk < 4; ++kk) {
        float4 u0 = *(const float4*)(a0p + kk * 32);
        float4 u1 = *(const float4*)(a0p + kk * 32 + 4);
        float4 v0 = *(const float4*)(a1p + kk * 32);
        float4 v1 = *(const float4*)(a1p + kk * 32 + 4);
        float r0, r1, r2, r3, r4, r5, r6, r7;
        uint4 h0, l0, h1, l1;
        h0.x = pack_hi(u0.x, u0.y, r0, r1);
        h0.y = pack_hi(u0.z, u0.w, r2, r3);
        h0.z = pack_hi(u1.x, u1.y, r4, r5);
        h0.w = pack_hi(u1.z, u1.w, r6, r7);
        l0.x = pack_lo(r0, r1); l0.y = pack_lo(r2, r3);
        l0.z = pack_lo(r4, r5); l0.w = pack_lo(r6, r7);
        h1.x = pack_hi(v0.x, v0.y, r0, r1);
        h1.y = pack_hi(v0.z, v0.w, r2, r3);
        h1.z = pack_hi(v1.x, v1.y, r4, r5);
        h1.w = pack_hi(v1.z, v1.w, r6, r7);
        l1.x = pack_lo(r0, r1); l1.y = pack_lo(r2, r3);
        l1.z = pack_lo(r4, r5); l1.w = pack_lo(r6, r7);
        bf16x8 a0hi = *(bf16x8*)&h0;
        bf16x8 a0lo = *(bf16x8*)&l0;
        bf16x8 a1hi = *(bf16x8*)&h1;
        bf16x8 a1lo = *(bf16x8*)&l1;

        int coff = ((kk * 4 + kg) ^ l15) * 8;
#pragma unroll
        for (int nf = 0; nf < 8; ++nf) {
            int bidx = (16 * nf + l15) * 128 + coff;
            bf16x8 bhi = *(const bf16x8*)&wl[bidx];
            bf16x8 blo = *(const bf16x8*)&wl[16384 + bidx];
            acc[0][nf] = __builtin_amdgcn_mfma_f32_16x16x32_bf16(a0hi, bhi, acc[0][nf], 0, 0, 0);
            acc[1][nf] = __builtin_amdgcn_mfma_f32_16x16x32_bf16(a1hi, bhi, acc[1][nf], 0, 0, 0);
            acc[0][nf] = __builtin_amdgcn_mfma_f32_16x16x32_bf16(a0lo, bhi, acc[0][nf], 0, 0, 0);
            acc[1][nf] = __builtin_amdgcn_mfma_f32_16x16x32_bf16(a1lo, bhi, acc[1][nf], 0, 0, 0);
            acc[0][nf] = __builtin_amdgcn_mfma_f32_16x16x32_bf16(a0hi, blo, acc[0][nf], 0, 0, 0);
            acc[1][nf] = __builtin_amdgcn_mfma_f32_16x16x32_bf16(a1hi, blo, acc[1][nf], 0, 0, 0);
        }
    }

    const int rofs = kg * 4;
#pragma unroll
    for (int nf = 0; nf < 8; ++nf) {
        int col = 16 * nf + l15;
        float bv = bias[col];
#pragma unroll
        for (int m = 0; m < 2; ++m) {
#pragma unroll
            for (int r = 0; r < 4; ++r) {
                int row = wrbase + 16 * m + rofs + r;
                if (row < NN) {
                    float h = acc[m][nf][r] + bv;
                    out[(size_t)row * D + col] = h > 0.f ? h : 0.f;
                }
            }
        }
    }
}

extern "C" void kernel_launch(void* const* d_in, const int* in_sizes, int n_in,
                              void* d_out, int out_size, void* d_ws, size_t ws_size,
                              hipStream_t stream) {
    const float* x    = (const float*)d_in[0];
    const int*   eidx = (const int*)d_in[1];   // [2, E] flat: src then dst
    const float* ew   = (const float*)d_in[2];
    const float* W    = (const float*)d_in[3];
    const float* bias = (const float*)d_in[4];
    float* out = (float*)d_out;

    const int* src = eidx;
    const int* dst = eidx + NE;

    // workspace layout (all 16B-aligned)
    char* base = (char*)d_ws;
    float*    agg  = (float*)base;                              // 25.6 MB
    unsigned* buck = (unsigned*)(base + 25600000);              // NN*CAP*4 = 12.8 MB
    unsigned* xb   = (unsigned*)(base + 25600000 + 12800000);   // 12.8 MB
    ushort*   wsp  = (ushort*)(base + 51200000);                // 64 KB
    int*      fillc   = (int*)(base + 51200000 + 65536);        // 200 KB
    int*      ovf_cnt = (int*)(base + 51200000 + 65536 + 200000);
    uint2*    ovf     = (uint2*)(base + 51200000 + 65536 + 200016);  // 512 KB

    prep<<<PREP_BLKS + 8, 256, 0, stream>>>(x, W, xb, wsp, fillc, ovf_cnt);
    fill_bucket<<<(NE + 255) / 256, 256, 0, stream>>>(src, dst, ew, fillc, buck, ovf_cnt, ovf);
    aggregate<<<(NN + 3) / 4, 256, 0, stream>>>(xb, fillc, buck, agg);
    ovf_fix<<<8, 256, 0, stream>>>(xb, ovf_cnt, ovf, agg);
    gemm_mfma<<<(NN + GBM - 1) / GBM, 256, 0, stream>>>(agg, wsp, bias, out);
}

// Round 6
// 87.485 us; speedup vs baseline: 12.8759x; 1.1695x over previous
//
#include <hip/hip_runtime.h>
#include <hip/hip_fp16.h>

#define NN 50000
#define NE 625000
#define D  128
#define CAP 64       // bucket capacity per node
#define NBIN 196     // ceil(NN/256): coarse bin = dst >> 8
#define BCAP 4096    // entries per coarse bin (mean 3189, sigma ~57)
#define BIN_BLOCKS 200
#define BIN_CHUNK 3125   // NE / BIN_BLOCKS
#define GBM 128      // GEMM rows per block
#define PREP_BLKS 3125   // NN*D/8/256

typedef __attribute__((ext_vector_type(8))) short bf16x8;
typedef __attribute__((ext_vector_type(4))) float f32x4;

__device__ inline unsigned f2bf_rne(float f) {
    unsigned u = __float_as_uint(f);
    u += 0x7FFFu + ((u >> 16) & 1u);
    return u >> 16;
}

// ---- W split helpers (fp32 -> bf16 hi + residual lo), pre-swizzled ----
__device__ inline unsigned pack_hi(float a, float b, float& ra, float& rb) {
    unsigned ba = __float_as_uint(a) & 0xffff0000u;
    unsigned bb = __float_as_uint(b) & 0xffff0000u;
    ra = a - __uint_as_float(ba);
    rb = b - __uint_as_float(bb);
    return (ba >> 16) | bb;
}
__device__ inline unsigned pack_lo(float ra, float rb) {
    return (__float_as_uint(ra) >> 16) | (__float_as_uint(rb) & 0xffff0000u);
}

// prep: zero bin counters + convert x -> bf16 + (tail blocks) split W
__global__ __launch_bounds__(256) void prep(const float* __restrict__ x,
                                            const float* __restrict__ W,
                                            unsigned* __restrict__ xb,
                                            ushort* __restrict__ wsp,
                                            int* __restrict__ binc,
                                            int* __restrict__ ovf_cnt) {
    if (blockIdx.x >= PREP_BLKS) {
        int g = (blockIdx.x - PREP_BLKS) * 256 + threadIdx.x;
        if (g >= 128 * 16) return;
        int col = g >> 4;
        int c16 = g & 15;
        const float4* wp = (const float4*)(W + (size_t)col * D + c16 * 8);
        float4 v0 = wp[0], v1 = wp[1];
        float r0, r1, r2, r3, r4, r5, r6, r7;
        uint4 hi, lo;
        hi.x = pack_hi(v0.x, v0.y, r0, r1);
        hi.y = pack_hi(v0.z, v0.w, r2, r3);
        hi.z = pack_hi(v1.x, v1.y, r4, r5);
        hi.w = pack_hi(v1.z, v1.w, r6, r7);
        lo.x = pack_lo(r0, r1); lo.y = pack_lo(r2, r3);
        lo.z = pack_lo(r4, r5); lo.w = pack_lo(r6, r7);
        int sidx = col * 16 + (c16 ^ (col & 15));
        ((uint4*)wsp)[sidx] = hi;
        ((uint4*)(wsp + 16384))[sidx] = lo;
        return;
    }
    int g = blockIdx.x * 256 + threadIdx.x;
    if (g < NBIN) binc[g] = 0;
    if (g == 0) *ovf_cnt = 0;
    const float4* xp = (const float4*)(x + (size_t)g * 8);
    float4 a = xp[0], b = xp[1];
    uint4 o;
    o.x = f2bf_rne(a.x) | (f2bf_rne(a.y) << 16);
    o.y = f2bf_rne(a.z) | (f2bf_rne(a.w) << 16);
    o.z = f2bf_rne(b.x) | (f2bf_rne(b.y) << 16);
    o.w = f2bf_rne(b.z) | (f2bf_rne(b.w) << 16);
    ((uint4*)xb)[g] = o;
}

// ---- phase A: coarse binning with LDS histogram + range reservation ----
__global__ __launch_bounds__(256) void bin_coarse(const int* __restrict__ src,
                                                  const int* __restrict__ dst,
                                                  const float* __restrict__ ew,
                                                  int* __restrict__ binc,
                                                  uint2* __restrict__ binbuf,
                                                  int* __restrict__ ovf_cnt,
                                                  uint2* __restrict__ ovf) {
    __shared__ int hcnt[NBIN];
    __shared__ int hbase[NBIN];
    __shared__ int hcur[NBIN];
    const int tid = threadIdx.x;
    const int e0 = blockIdx.x * BIN_CHUNK;
    const int e1 = min(e0 + BIN_CHUNK, NE);

    for (int i = tid; i < NBIN; i += 256) hcnt[i] = 0;
    __syncthreads();
    for (int e = e0 + tid; e < e1; e += 256)
        atomicAdd(&hcnt[dst[e] >> 8], 1);
    __syncthreads();
    for (int i = tid; i < NBIN; i += 256) {
        int c = hcnt[i];
        hbase[i] = c ? atomicAdd(&binc[i], c) : 0;
        hcur[i] = 0;
    }
    __syncthreads();
    for (int e = e0 + tid; e < e1; e += 256) {
        int d = dst[e];
        int bin = d >> 8;
        unsigned entry = ((unsigned)src[e] << 16) |
                         (unsigned)__half_as_ushort(__float2half(ew[e]));
        int slot = hbase[bin] + atomicAdd(&hcur[bin], 1);
        if (slot < BCAP) {
            binbuf[(size_t)bin * BCAP + slot] = make_uint2((unsigned)d, entry);
        } else {
            int o = atomicAdd(ovf_cnt, 1);
            ovf[o] = make_uint2((unsigned)d, entry);
        }
    }
}

// ---- phase B: per-bin scatter into node buckets (one block per bin) ----
__global__ __launch_bounds__(256) void bin_fill(const int* __restrict__ binc,
                                                const uint2* __restrict__ binbuf,
                                                int* __restrict__ fillc,
                                                unsigned* __restrict__ buck,
                                                int* __restrict__ ovf_cnt,
                                                uint2* __restrict__ ovf) {
    __shared__ int lcnt[256];
    const int tid = threadIdx.x;
    const int bin = blockIdx.x;
    lcnt[tid] = 0;
    __syncthreads();
    int n = binc[bin];
    if (n > BCAP) n = BCAP;
    const uint2* bp = binbuf + (size_t)bin * BCAP;
    for (int i = tid; i < n; i += 256) {
        uint2 q = bp[i];
        int d = (int)q.x;
        int p = atomicAdd(&lcnt[d & 255], 1);
        if (p < CAP) {
            buck[(size_t)d * CAP + p] = q.y;
        } else {
            int o = atomicAdd(ovf_cnt, 1);
            ovf[o] = q;
        }
    }
    __syncthreads();
    int node = bin * 256 + tid;
    if (node < NN) fillc[node] = lcnt[tid];
}

// ---- aggregate (gather, bf16 x, 4B entries) ----
__global__ __launch_bounds__(256) void aggregate(const unsigned* __restrict__ xb,
                                                 const int* __restrict__ fillc,
                                                 const unsigned* __restrict__ buck,
                                                 float* __restrict__ agg) {
    int node = blockIdx.x * 4 + (threadIdx.x >> 6);
    int t    = threadIdx.x & 63;
    if (node >= NN) return;
    int cnt = fillc[node];
    if (cnt > CAP) cnt = CAP;
    const unsigned* bp = buck + (size_t)node * CAP;
    float2 acc{0.f, 0.f};
    int i = 0;
    for (; i + 3 < cnt; i += 4) {
        unsigned q0 = bp[i], q1 = bp[i + 1], q2 = bp[i + 2], q3 = bp[i + 3];
        unsigned u0 = xb[(size_t)(q0 >> 16) * 64 + t];
        unsigned u1 = xb[(size_t)(q1 >> 16) * 64 + t];
        unsigned u2 = xb[(size_t)(q2 >> 16) * 64 + t];
        unsigned u3 = xb[(size_t)(q3 >> 16) * 64 + t];
        float w0 = __half2float(__ushort_as_half((ushort)(q0 & 0xffffu)));
        float w1 = __half2float(__ushort_as_half((ushort)(q1 & 0xffffu)));
        float w2 = __half2float(__ushort_as_half((ushort)(q2 & 0xffffu)));
        float w3 = __half2float(__ushort_as_half((ushort)(q3 & 0xffffu)));
        acc.x += __uint_as_float(u0 << 16) * w0;
        acc.y += __uint_as_float(u0 & 0xffff0000u) * w0;
        acc.x += __uint_as_float(u1 << 16) * w1;
        acc.y += __uint_as_float(u1 & 0xffff0000u) * w1;
        acc.x += __uint_as_float(u2 << 16) * w2;
        acc.y += __uint_as_float(u2 & 0xffff0000u) * w2;
        acc.x += __uint_as_float(u3 << 16) * w3;
        acc.y += __uint_as_float(u3 & 0xffff0000u) * w3;
    }
    for (; i < cnt; ++i) {
        unsigned q0 = bp[i];
        unsigned u0 = xb[(size_t)(q0 >> 16) * 64 + t];
        float w0 = __half2float(__ushort_as_half((ushort)(q0 & 0xffffu)));
        acc.x += __uint_as_float(u0 << 16) * w0;
        acc.y += __uint_as_float(u0 & 0xffff0000u) * w0;
    }
    reinterpret_cast<float2*>(agg)[(size_t)node * 64 + t] = acc;
}

// ---- overflow fixup (statistically never; correctness net) ----
__global__ __launch_bounds__(256) void ovf_fix(const unsigned* __restrict__ xb,
                                               const int* __restrict__ ovf_cnt,
                                               const uint2* __restrict__ ovf,
                                               float* __restrict__ agg) {
    int n = *ovf_cnt;
    int widx = (blockIdx.x * 256 + threadIdx.x) >> 6;
    int t = threadIdx.x & 63;
    int nw = gridDim.x * 4;
    for (int o = widx; o < n; o += nw) {
        unsigned d = ovf[o].x;
        unsigned q = ovf[o].y;
        unsigned u = xb[(size_t)(q >> 16) * 64 + t];
        float w = __half2float(__ushort_as_half((ushort)(q & 0xffffu)));
        atomicAdd(&agg[(size_t)d * D + 2 * t],     __uint_as_float(u << 16) * w);
        atomicAdd(&agg[(size_t)d * D + 2 * t + 1], __uint_as_float(u & 0xffff0000u) * w);
    }
}

// ---- GEMM via bf16 MFMA, 3-term split precision ----
__global__ __launch_bounds__(256) void gemm_mfma(const float* __restrict__ agg,
                                                 const ushort* __restrict__ wsp,
                                                 const float* __restrict__ bias,
                                                 float* __restrict__ out) {
    __shared__ ushort wl[32768];
    const int tid = threadIdx.x;
    {
        const uint4* s = (const uint4*)wsp;
        uint4* d = (uint4*)wl;
#pragma unroll
        for (int i = 0; i < 16; ++i)
            d[i * 256 + tid] = s[i * 256 + tid];
    }
    __syncthreads();

    const int wid = tid >> 6, lane = tid & 63;
    const int l15 = lane & 15, kg = lane >> 4;
    const int wrbase = blockIdx.x * GBM + wid * 32;

    f32x4 acc[2][8];
    const f32x4 fz = {0.f, 0.f, 0.f, 0.f};
#pragma unroll
    for (int m = 0; m < 2; ++m)
#pragma unroll
        for (int n = 0; n < 8; ++n) acc[m][n] = fz;

    int arow0 = wrbase + l15;
    int arow1 = wrbase + 16 + l15;
    const float* a0p = agg + (size_t)(arow0 < NN ? arow0 : NN - 1) * D + kg * 8;
    const float* a1p = agg + (size_t)(arow1 < NN ? arow1 : NN - 1) * D + kg * 8;

#pragma unroll
    for (int kk = 0; kk < 4; ++kk) {
        float4 u0 = *(const float4*)(a0p + kk * 32);
        float4 u1 = *(const float4*)(a0p + kk * 32 + 4);
        float4 v0 = *(const float4*)(a1p + kk * 32);
        float4 v1 = *(const float4*)(a1p + kk * 32 + 4);
        float r0, r1, r2, r3, r4, r5, r6, r7;
        uint4 h0, l0, h1, l1;
        h0.x = pack_hi(u0.x, u0.y, r0, r1);
        h0.y = pack_hi(u0.z, u0.w, r2, r3);
        h0.z = pack_hi(u1.x, u1.y, r4, r5);
        h0.w = pack_hi(u1.z, u1.w, r6, r7);
        l0.x = pack_lo(r0, r1); l0.y = pack_lo(r2, r3);
        l0.z = pack_lo(r4, r5); l0.w = pack_lo(r6, r7);
        h1.x = pack_hi(v0.x, v0.y, r0, r1);
        h1.y = pack_hi(v0.z, v0.w, r2, r3);
        h1.z = pack_hi(v1.x, v1.y, r4, r5);
        h1.w = pack_hi(v1.z, v1.w, r6, r7);
        l1.x = pack_lo(r0, r1); l1.y = pack_lo(r2, r3);
        l1.z = pack_lo(r4, r5); l1.w = pack_lo(r6, r7);
        bf16x8 a0hi = *(bf16x8*)&h0;
        bf16x8 a0lo = *(bf16x8*)&l0;
        bf16x8 a1hi = *(bf16x8*)&h1;
        bf16x8 a1lo = *(bf16x8*)&l1;

        int coff = ((kk * 4 + kg) ^ l15) * 8;
#pragma unroll
        for (int nf = 0; nf < 8; ++nf) {
            int bidx = (16 * nf + l15) * 128 + coff;
            bf16x8 bhi = *(const bf16x8*)&wl[bidx];
            bf16x8 blo = *(const bf16x8*)&wl[16384 + bidx];
            acc[0][nf] = __builtin_amdgcn_mfma_f32_16x16x32_bf16(a0hi, bhi, acc[0][nf], 0, 0, 0);
            acc[1][nf] = __builtin_amdgcn_mfma_f32_16x16x32_bf16(a1hi, bhi, acc[1][nf], 0, 0, 0);
            acc[0][nf] = __builtin_amdgcn_mfma_f32_16x16x32_bf16(a0lo, bhi, acc[0][nf], 0, 0, 0);
            acc[1][nf] = __builtin_amdgcn_mfma_f32_16x16x32_bf16(a1lo, bhi, acc[1][nf], 0, 0, 0);
            acc[0][nf] = __builtin_amdgcn_mfma_f32_16x16x32_bf16(a0hi, blo, acc[0][nf], 0, 0, 0);
            acc[1][nf] = __builtin_amdgcn_mfma_f32_16x16x32_bf16(a1hi, blo, acc[1][nf], 0, 0, 0);
        }
    }

    const int rofs = kg * 4;
#pragma unroll
    for (int nf = 0; nf < 8; ++nf) {
        int col = 16 * nf + l15;
        float bv = bias[col];
#pragma unroll
        for (int m = 0; m < 2; ++m) {
#pragma unroll
            for (int r = 0; r < 4; ++r) {
                int row = wrbase + 16 * m + rofs + r;
                if (row < NN) {
                    float h = acc[m][nf][r] + bv;
                    out[(size_t)row * D + col] = h > 0.f ? h : 0.f;
                }
            }
        }
    }
}

extern "C" void kernel_launch(void* const* d_in, const int* in_sizes, int n_in,
                              void* d_out, int out_size, void* d_ws, size_t ws_size,
                              hipStream_t stream) {
    const float* x    = (const float*)d_in[0];
    const int*   eidx = (const int*)d_in[1];   // [2, E] flat: src then dst
    const float* ew   = (const float*)d_in[2];
    const float* W    = (const float*)d_in[3];
    const float* bias = (const float*)d_in[4];
    float* out = (float*)d_out;

    const int* src = eidx;
    const int* dst = eidx + NE;

    // workspace layout (binbuf aliases agg: dead before aggregate writes agg)
    char* base = (char*)d_ws;
    float*    agg    = (float*)base;                            // 25.6 MB
    uint2*    binbuf = (uint2*)base;                            // NBIN*BCAP*8 = 6.4 MB (alias)
    unsigned* buck   = (unsigned*)(base + 25600000);            // NN*CAP*4 = 12.8 MB
    unsigned* xb     = (unsigned*)(base + 25600000 + 12800000); // 12.8 MB
    ushort*   wsp    = (ushort*)(base + 51200000);              // 64 KB
    int*      fillc   = (int*)(base + 51200000 + 65536);        // 200 KB
    int*      binc    = (int*)(base + 51200000 + 65536 + 200000);   // 784 B
    int*      ovf_cnt = (int*)(base + 51200000 + 65536 + 200000 + 1024);
    uint2*    ovf     = (uint2*)(base + 51200000 + 65536 + 200000 + 1024 + 16); // 512 KB

    prep<<<PREP_BLKS + 8, 256, 0, stream>>>(x, W, xb, wsp, binc, ovf_cnt);
    bin_coarse<<<BIN_BLOCKS, 256, 0, stream>>>(src, dst, ew, binc, binbuf, ovf_cnt, ovf);
    bin_fill<<<NBIN, 256, 0, stream>>>(binc, binbuf, fillc, buck, ovf_cnt, ovf);
    aggregate<<<(NN + 3) / 4, 256, 0, stream>>>(xb, fillc, buck, agg);
    ovf_fix<<<8, 256, 0, stream>>>(xb, ovf_cnt, ovf, agg);
    gemm_mfma<<<(NN + GBM - 1) / GBM, 256, 0, stream>>>(agg, wsp, bias, out);
}

// Round 7
// 85.504 us; speedup vs baseline: 13.1742x; 1.0232x over previous
//
#include <hip/hip_runtime.h>
#include <hip/hip_fp16.h>

#define NN 50000
#define NE 625000
#define D  128
#define CAP 64       // bucket capacity per node
#define NBIN 196     // ceil(NN/256): coarse bin = dst >> 8
#define BCAP 4096    // entries per coarse bin (mean 3189, sigma ~57)
#define BIN_BLOCKS 200
#define BIN_CHUNK 3125   // NE / BIN_BLOCKS
#define GBM 128      // GEMM rows per block
#define PREP_BLKS 3125   // NN*D/8/256
#define MEGA_X  BIN_BLOCKS                // x-convert blocks start here
#define MEGA_W  (BIN_BLOCKS + PREP_BLKS)  // W-split blocks start here (3325)
#define MEGA_GRID (MEGA_W + 8)            // 3333

typedef __attribute__((ext_vector_type(8))) short bf16x8;
typedef __attribute__((ext_vector_type(4))) float f32x4;

__device__ inline unsigned f2bf_rne(float f) {
    unsigned u = __float_as_uint(f);
    u += 0x7FFFu + ((u >> 16) & 1u);
    return u >> 16;
}

// ---- W split helpers (fp32 -> bf16 hi + residual lo), pre-swizzled ----
__device__ inline unsigned pack_hi(float a, float b, float& ra, float& rb) {
    unsigned ba = __float_as_uint(a) & 0xffff0000u;
    unsigned bb = __float_as_uint(b) & 0xffff0000u;
    ra = a - __uint_as_float(ba);
    rb = b - __uint_as_float(bb);
    return (ba >> 16) | bb;
}
__device__ inline unsigned pack_lo(float ra, float rb) {
    return (__float_as_uint(ra) >> 16) | (__float_as_uint(rb) & 0xffff0000u);
}

// ---- mega1: [0,200) bin_coarse | [200,3325) x->bf16 | [3325,3333) W-split ----
// requires binc[NBIN] and ovf_cnt pre-zeroed (hipMemsetAsync)
__global__ __launch_bounds__(256) void mega1(const float* __restrict__ x,
                                             const float* __restrict__ W,
                                             const int* __restrict__ src,
                                             const int* __restrict__ dst,
                                             const float* __restrict__ ew,
                                             unsigned* __restrict__ xb,
                                             ushort* __restrict__ wsp,
                                             int* __restrict__ binc,
                                             uint2* __restrict__ binbuf,
                                             int* __restrict__ ovf_cnt,
                                             uint2* __restrict__ ovf) {
    const int tid = threadIdx.x;
    if (blockIdx.x < MEGA_X) {
        // ---- coarse binning with per-wave LDS histograms + range reservation ----
        __shared__ int hcnt[4][NBIN];
        __shared__ int hbase[NBIN];
        __shared__ int hcur[NBIN];
        const int wv = tid >> 6;
        const int e0 = blockIdx.x * BIN_CHUNK;
        const int e1 = min(e0 + BIN_CHUNK, NE);
        for (int i = tid; i < NBIN; i += 256) {
            hcnt[0][i] = 0; hcnt[1][i] = 0; hcnt[2][i] = 0; hcnt[3][i] = 0;
        }
        __syncthreads();
        for (int e = e0 + tid; e < e1; e += 256)
            atomicAdd(&hcnt[wv][dst[e] >> 8], 1);
        __syncthreads();
        for (int i = tid; i < NBIN; i += 256) {
            int c = hcnt[0][i] + hcnt[1][i] + hcnt[2][i] + hcnt[3][i];
            hbase[i] = c ? atomicAdd(&binc[i], c) : 0;
            hcur[i] = 0;
        }
        __syncthreads();
        for (int e = e0 + tid; e < e1; e += 256) {
            int d = dst[e];
            int bin = d >> 8;
            unsigned entry = ((unsigned)src[e] << 16) |
                             (unsigned)__half_as_ushort(__float2half(ew[e]));
            int slot = hbase[bin] + atomicAdd(&hcur[bin], 1);
            if (slot < BCAP) {
                binbuf[(size_t)bin * BCAP + slot] = make_uint2((unsigned)d, entry);
            } else {
                int o = atomicAdd(ovf_cnt, 1);
                ovf[o] = make_uint2((unsigned)d, entry);
            }
        }
        return;
    }
    if (blockIdx.x < MEGA_W) {
        // ---- x -> bf16 ----
        int g = (blockIdx.x - MEGA_X) * 256 + tid;      // < 800000
        const float4* xp = (const float4*)(x + (size_t)g * 8);
        float4 a = xp[0], b = xp[1];
        uint4 o;
        o.x = f2bf_rne(a.x) | (f2bf_rne(a.y) << 16);
        o.y = f2bf_rne(a.z) | (f2bf_rne(a.w) << 16);
        o.z = f2bf_rne(b.x) | (f2bf_rne(b.y) << 16);
        o.w = f2bf_rne(b.z) | (f2bf_rne(b.w) << 16);
        ((uint4*)xb)[g] = o;
        return;
    }
    // ---- W split (pre-swizzled) ----
    int g = (blockIdx.x - MEGA_W) * 256 + tid;
    if (g >= 128 * 16) return;
    int col = g >> 4;
    int c16 = g & 15;
    const float4* wp = (const float4*)(W + (size_t)col * D + c16 * 8);
    float4 v0 = wp[0], v1 = wp[1];
    float r0, r1, r2, r3, r4, r5, r6, r7;
    uint4 hi, lo;
    hi.x = pack_hi(v0.x, v0.y, r0, r1);
    hi.y = pack_hi(v0.z, v0.w, r2, r3);
    hi.z = pack_hi(v1.x, v1.y, r4, r5);
    hi.w = pack_hi(v1.z, v1.w, r6, r7);
    lo.x = pack_lo(r0, r1); lo.y = pack_lo(r2, r3);
    lo.z = pack_lo(r4, r5); lo.w = pack_lo(r6, r7);
    int sidx = col * 16 + (c16 ^ (col & 15));
    ((uint4*)wsp)[sidx] = hi;
    ((uint4*)(wsp + 16384))[sidx] = lo;
}

// ---- phase B: per-bin scatter into node buckets (one block per bin) ----
__global__ __launch_bounds__(256) void bin_fill(const int* __restrict__ binc,
                                                const uint2* __restrict__ binbuf,
                                                int* __restrict__ fillc,
                                                unsigned* __restrict__ buck,
                                                int* __restrict__ ovf_cnt,
                                                uint2* __restrict__ ovf) {
    __shared__ int lcnt[256];
    const int tid = threadIdx.x;
    const int bin = blockIdx.x;
    lcnt[tid] = 0;
    __syncthreads();
    int n = binc[bin];
    if (n > BCAP) n = BCAP;
    const uint2* bp = binbuf + (size_t)bin * BCAP;
    for (int i = tid; i < n; i += 256) {
        uint2 q = bp[i];
        int d = (int)q.x;
        int p = atomicAdd(&lcnt[d & 255], 1);
        if (p < CAP) {
            buck[(size_t)d * CAP + p] = q.y;
        } else {
            int o = atomicAdd(ovf_cnt, 1);
            ovf[o] = q;
        }
    }
    __syncthreads();
    int node = bin * 256 + tid;
    if (node < NN) fillc[node] = lcnt[tid];
}

// ---- aggregate: 2 nodes per wave, lane owns 4 dims (uint2 = 4 bf16) ----
// grid 6250 x 256: 4 waves/block x 2 nodes = 8 nodes/block; 6250*8 = 50000
__global__ __launch_bounds__(256) void aggregate(const unsigned* __restrict__ xb,
                                                 const int* __restrict__ fillc,
                                                 const unsigned* __restrict__ buck,
                                                 const int* __restrict__ ovf_cnt,
                                                 const uint2* __restrict__ ovf,
                                                 float* __restrict__ agg) {
    const int node = blockIdx.x * 8 + ((threadIdx.x >> 5));   // 8 half-waves/block
    const int t = threadIdx.x & 31;                            // owns dims 4t..4t+3
    int cnt = fillc[node];
    if (cnt > CAP) cnt = CAP;
    const unsigned* bp = buck + (size_t)node * CAP;
    const uint2* x2 = (const uint2*)xb;
    float4 acc = {0.f, 0.f, 0.f, 0.f};
    int i = 0;
    for (; i + 3 < cnt; i += 4) {
        unsigned q0 = bp[i], q1 = bp[i + 1], q2 = bp[i + 2], q3 = bp[i + 3];
        uint2 u0 = x2[(size_t)(q0 >> 16) * 32 + t];
        uint2 u1 = x2[(size_t)(q1 >> 16) * 32 + t];
        uint2 u2 = x2[(size_t)(q2 >> 16) * 32 + t];
        uint2 u3 = x2[(size_t)(q3 >> 16) * 32 + t];
        float w0 = __half2float(__ushort_as_half((ushort)(q0 & 0xffffu)));
        float w1 = __half2float(__ushort_as_half((ushort)(q1 & 0xffffu)));
        float w2 = __half2float(__ushort_as_half((ushort)(q2 & 0xffffu)));
        float w3 = __half2float(__ushort_as_half((ushort)(q3 & 0xffffu)));
        acc.x += __uint_as_float(u0.x << 16) * w0;
        acc.y += __uint_as_float(u0.x & 0xffff0000u) * w0;
        acc.z += __uint_as_float(u0.y << 16) * w0;
        acc.w += __uint_as_float(u0.y & 0xffff0000u) * w0;
        acc.x += __uint_as_float(u1.x << 16) * w1;
        acc.y += __uint_as_float(u1.x & 0xffff0000u) * w1;
        acc.z += __uint_as_float(u1.y << 16) * w1;
        acc.w += __uint_as_float(u1.y & 0xffff0000u) * w1;
        acc.x += __uint_as_float(u2.x << 16) * w2;
        acc.y += __uint_as_float(u2.x & 0xffff0000u) * w2;
        acc.z += __uint_as_float(u2.y << 16) * w2;
        acc.w += __uint_as_float(u2.y & 0xffff0000u) * w2;
        acc.x += __uint_as_float(u3.x << 16) * w3;
        acc.y += __uint_as_float(u3.x & 0xffff0000u) * w3;
        acc.z += __uint_as_float(u3.y << 16) * w3;
        acc.w += __uint_as_float(u3.y & 0xffff0000u) * w3;
    }
    for (; i < cnt; ++i) {
        unsigned q0 = bp[i];
        uint2 u0 = x2[(size_t)(q0 >> 16) * 32 + t];
        float w0 = __half2float(__ushort_as_half((ushort)(q0 & 0xffffu)));
        acc.x += __uint_as_float(u0.x << 16) * w0;
        acc.y += __uint_as_float(u0.x & 0xffff0000u) * w0;
        acc.z += __uint_as_float(u0.y << 16) * w0;
        acc.w += __uint_as_float(u0.y & 0xffff0000u) * w0;
    }
    // overflow entries (statistically never; correctness net)
    int n = *ovf_cnt;
    for (int o = 0; o < n; ++o) {
        uint2 q = ovf[o];
        if ((int)q.x == node) {
            uint2 u = x2[(size_t)(q.y >> 16) * 32 + t];
            float w = __half2float(__ushort_as_half((ushort)(q.y & 0xffffu)));
            acc.x += __uint_as_float(u.x << 16) * w;
            acc.y += __uint_as_float(u.x & 0xffff0000u) * w;
            acc.z += __uint_as_float(u.y << 16) * w;
            acc.w += __uint_as_float(u.y & 0xffff0000u) * w;
        }
    }
    ((float4*)agg)[(size_t)node * 32 + t] = acc;
}

// ---- GEMM via bf16 MFMA, 3-term split precision ----
__global__ __launch_bounds__(256) void gemm_mfma(const float* __restrict__ agg,
                                                 const ushort* __restrict__ wsp,
                                                 const float* __restrict__ bias,
                                                 float* __restrict__ out) {
    __shared__ ushort wl[32768];
    const int tid = threadIdx.x;
    {
        const uint4* s = (const uint4*)wsp;
        uint4* d = (uint4*)wl;
#pragma unroll
        for (int i = 0; i < 16; ++i)
            d[i * 256 + tid] = s[i * 256 + tid];
    }
    __syncthreads();

    const int wid = tid >> 6, lane = tid & 63;
    const int l15 = lane & 15, kg = lane >> 4;
    const int wrbase = blockIdx.x * GBM + wid * 32;

    f32x4 acc[2][8];
    const f32x4 fz = {0.f, 0.f, 0.f, 0.f};
#pragma unroll
    for (int m = 0; m < 2; ++m)
#pragma unroll
        for (int n = 0; n < 8; ++n) acc[m][n] = fz;

    int arow0 = wrbase + l15;
    int arow1 = wrbase + 16 + l15;
    const float* a0p = agg + (size_t)(arow0 < NN ? arow0 : NN - 1) * D + kg * 8;
    const float* a1p = agg + (size_t)(arow1 < NN ? arow1 : NN - 1) * D + kg * 8;

#pragma unroll
    for (int kk = 0; kk < 4; ++kk) {
        float4 u0 = *(const float4*)(a0p + kk * 32);
        float4 u1 = *(const float4*)(a0p + kk * 32 + 4);
        float4 v0 = *(const float4*)(a1p + kk * 32);
        float4 v1 = *(const float4*)(a1p + kk * 32 + 4);
        float r0, r1, r2, r3, r4, r5, r6, r7;
        uint4 h0, l0, h1, l1;
        h0.x = pack_hi(u0.x, u0.y, r0, r1);
        h0.y = pack_hi(u0.z, u0.w, r2, r3);
        h0.z = pack_hi(u1.x, u1.y, r4, r5);
        h0.w = pack_hi(u1.z, u1.w, r6, r7);
        l0.x = pack_lo(r0, r1); l0.y = pack_lo(r2, r3);
        l0.z = pack_lo(r4, r5); l0.w = pack_lo(r6, r7);
        h1.x = pack_hi(v0.x, v0.y, r0, r1);
        h1.y = pack_hi(v0.z, v0.w, r2, r3);
        h1.z = pack_hi(v1.x, v1.y, r4, r5);
        h1.w = pack_hi(v1.z, v1.w, r6, r7);
        l1.x = pack_lo(r0, r1); l1.y = pack_lo(r2, r3);
        l1.z = pack_lo(r4, r5); l1.w = pack_lo(r6, r7);
        bf16x8 a0hi = *(bf16x8*)&h0;
        bf16x8 a0lo = *(bf16x8*)&l0;
        bf16x8 a1hi = *(bf16x8*)&h1;
        bf16x8 a1lo = *(bf16x8*)&l1;

        int coff = ((kk * 4 + kg) ^ l15) * 8;
#pragma unroll
        for (int nf = 0; nf < 8; ++nf) {
            int bidx = (16 * nf + l15) * 128 + coff;
            bf16x8 bhi = *(const bf16x8*)&wl[bidx];
            bf16x8 blo = *(const bf16x8*)&wl[16384 + bidx];
            acc[0][nf] = __builtin_amdgcn_mfma_f32_16x16x32_bf16(a0hi, bhi, acc[0][nf], 0, 0, 0);
            acc[1][nf] = __builtin_amdgcn_mfma_f32_16x16x32_bf16(a1hi, bhi, acc[1][nf], 0, 0, 0);
            acc[0][nf] = __builtin_amdgcn_mfma_f32_16x16x32_bf16(a0lo, bhi, acc[0][nf], 0, 0, 0);
            acc[1][nf] = __builtin_amdgcn_mfma_f32_16x16x32_bf16(a1lo, bhi, acc[1][nf], 0, 0, 0);
            acc[0][nf] = __builtin_amdgcn_mfma_f32_16x16x32_bf16(a0hi, blo, acc[0][nf], 0, 0, 0);
            acc[1][nf] = __builtin_amdgcn_mfma_f32_16x16x32_bf16(a1hi, blo, acc[1][nf], 0, 0, 0);
        }
    }

    const int rofs = kg * 4;
#pragma unroll
    for (int nf = 0; nf < 8; ++nf) {
        int col = 16 * nf + l15;
        float bv = bias[col];
#pragma unroll
        for (int m = 0; m < 2; ++m) {
#pragma unroll
            for (int r = 0; r < 4; ++r) {
                int row = wrbase + 16 * m + rofs + r;
                if (row < NN) {
                    float h = acc[m][nf][r] + bv;
                    out[(size_t)row * D + col] = h > 0.f ? h : 0.f;
                }
            }
        }
    }
}

extern "C" void kernel_launch(void* const* d_in, const int* in_sizes, int n_in,
                              void* d_out, int out_size, void* d_ws, size_t ws_size,
                              hipStream_t stream) {
    const float* x    = (const float*)d_in[0];
    const int*   eidx = (const int*)d_in[1];   // [2, E] flat: src then dst
    const float* ew   = (const float*)d_in[2];
    const float* W    = (const float*)d_in[3];
    const float* bias = (const float*)d_in[4];
    float* out = (float*)d_out;

    const int* src = eidx;
    const int* dst = eidx + NE;

    // workspace layout (binbuf aliases agg: dead before aggregate writes agg)
    char* base = (char*)d_ws;
    float*    agg    = (float*)base;                            // 25.6 MB
    uint2*    binbuf = (uint2*)base;                            // NBIN*BCAP*8 = 6.4 MB (alias)
    unsigned* buck   = (unsigned*)(base + 25600000);            // NN*CAP*4 = 12.8 MB
    unsigned* xb     = (unsigned*)(base + 25600000 + 12800000); // 12.8 MB
    ushort*   wsp    = (ushort*)(base + 51200000);              // 64 KB
    int*      fillc   = (int*)(base + 51200000 + 65536);        // 200 KB
    int*      binc    = (int*)(base + 51200000 + 65536 + 200000);   // 784 B
    int*      ovf_cnt = (int*)((char*)binc + NBIN * 4);             // adjacent: one memset
    uint2*    ovf     = (uint2*)(base + 51200000 + 65536 + 200000 + 1024); // 512 KB

    hipMemsetAsync(binc, 0, NBIN * 4 + 4, stream);
    mega1<<<MEGA_GRID, 256, 0, stream>>>(x, W, src, dst, ew, xb, wsp, binc, binbuf, ovf_cnt, ovf);
    bin_fill<<<NBIN, 256, 0, stream>>>(binc, binbuf, fillc, buck, ovf_cnt, ovf);
    aggregate<<<6250, 256, 0, stream>>>(xb, fillc, buck, ovf_cnt, ovf, agg);
    gemm_mfma<<<(NN + GBM - 1) / GBM, 256, 0, stream>>>(agg, wsp, bias, out);
}

// Round 8
// 79.721 us; speedup vs baseline: 14.1299x; 1.0725x over previous
//
#include <hip/hip_runtime.h>
#include <hip/hip_fp16.h>

#define NN 50000
#define NE 625000
#define D  128
#define CAP 64       // bucket capacity per node
#define NBIN 196     // ceil(NN/256): coarse bin = dst >> 8
#define BCAP 4096    // entries per coarse bin (mean 3189, sigma ~57)
#define BIN_BLOCKS 200
#define BIN_CHUNK 3125   // NE / BIN_BLOCKS
#define GBM 128      // GEMM rows per block
#define PREP_BLKS 3125   // NN*D/8/256
#define MEGA_X  BIN_BLOCKS
#define MEGA_W  (BIN_BLOCKS + PREP_BLKS)
#define MEGA_GRID (MEGA_W + 8)

typedef __attribute__((ext_vector_type(8))) short bf16x8;
typedef __attribute__((ext_vector_type(4))) float f32x4;

__device__ inline unsigned f2bf_rne(float f) {
    unsigned u = __float_as_uint(f);
    u += 0x7FFFu + ((u >> 16) & 1u);
    return u >> 16;
}

// ---- W split helpers (fp32 -> bf16 hi + residual lo), pre-swizzled ----
__device__ inline unsigned pack_hi(float a, float b, float& ra, float& rb) {
    unsigned ba = __float_as_uint(a) & 0xffff0000u;
    unsigned bb = __float_as_uint(b) & 0xffff0000u;
    ra = a - __uint_as_float(ba);
    rb = b - __uint_as_float(bb);
    return (ba >> 16) | bb;
}
__device__ inline unsigned pack_lo(float ra, float rb) {
    return (__float_as_uint(ra) >> 16) | (__float_as_uint(rb) & 0xffff0000u);
}

// ---- mega1: [0,200) bin_coarse | [200,3325) x->bf16 | [3325,3333) W-split ----
__global__ __launch_bounds__(256) void mega1(const float* __restrict__ x,
                                             const float* __restrict__ W,
                                             const int* __restrict__ src,
                                             const int* __restrict__ dst,
                                             const float* __restrict__ ew,
                                             unsigned* __restrict__ xb,
                                             ushort* __restrict__ wsp,
                                             int* __restrict__ binc,
                                             uint2* __restrict__ binbuf,
                                             int* __restrict__ ovf_cnt,
                                             uint2* __restrict__ ovf) {
    const int tid = threadIdx.x;
    if (blockIdx.x < MEGA_X) {
        __shared__ int hcnt[4][NBIN];
        __shared__ int hbase[NBIN];
        __shared__ int hcur[NBIN];
        const int wv = tid >> 6;
        const int e0 = blockIdx.x * BIN_CHUNK;
        const int e1 = min(e0 + BIN_CHUNK, NE);
        for (int i = tid; i < NBIN; i += 256) {
            hcnt[0][i] = 0; hcnt[1][i] = 0; hcnt[2][i] = 0; hcnt[3][i] = 0;
        }
        __syncthreads();
        for (int e = e0 + tid; e < e1; e += 256)
            atomicAdd(&hcnt[wv][dst[e] >> 8], 1);
        __syncthreads();
        for (int i = tid; i < NBIN; i += 256) {
            int c = hcnt[0][i] + hcnt[1][i] + hcnt[2][i] + hcnt[3][i];
            hbase[i] = c ? atomicAdd(&binc[i], c) : 0;
            hcur[i] = 0;
        }
        __syncthreads();
        for (int e = e0 + tid; e < e1; e += 256) {
            int d = dst[e];
            int bin = d >> 8;
            unsigned entry = ((unsigned)src[e] << 16) |
                             (unsigned)__half_as_ushort(__float2half(ew[e]));
            int slot = hbase[bin] + atomicAdd(&hcur[bin], 1);
            if (slot < BCAP) {
                binbuf[(size_t)bin * BCAP + slot] = make_uint2((unsigned)d, entry);
            } else {
                int o = atomicAdd(ovf_cnt, 1);
                ovf[o] = make_uint2((unsigned)d, entry);
            }
        }
        return;
    }
    if (blockIdx.x < MEGA_W) {
        int g = (blockIdx.x - MEGA_X) * 256 + tid;
        const float4* xp = (const float4*)(x + (size_t)g * 8);
        float4 a = xp[0], b = xp[1];
        uint4 o;
        o.x = f2bf_rne(a.x) | (f2bf_rne(a.y) << 16);
        o.y = f2bf_rne(a.z) | (f2bf_rne(a.w) << 16);
        o.z = f2bf_rne(b.x) | (f2bf_rne(b.y) << 16);
        o.w = f2bf_rne(b.z) | (f2bf_rne(b.w) << 16);
        ((uint4*)xb)[g] = o;
        return;
    }
    int g = (blockIdx.x - MEGA_W) * 256 + tid;
    if (g >= 128 * 16) return;
    int col = g >> 4;
    int c16 = g & 15;
    const float4* wp = (const float4*)(W + (size_t)col * D + c16 * 8);
    float4 v0 = wp[0], v1 = wp[1];
    float r0, r1, r2, r3, r4, r5, r6, r7;
    uint4 hi, lo;
    hi.x = pack_hi(v0.x, v0.y, r0, r1);
    hi.y = pack_hi(v0.z, v0.w, r2, r3);
    hi.z = pack_hi(v1.x, v1.y, r4, r5);
    hi.w = pack_hi(v1.z, v1.w, r6, r7);
    lo.x = pack_lo(r0, r1); lo.y = pack_lo(r2, r3);
    lo.z = pack_lo(r4, r5); lo.w = pack_lo(r6, r7);
    int sidx = col * 16 + (c16 ^ (col & 15));
    ((uint4*)wsp)[sidx] = hi;
    ((uint4*)(wsp + 16384))[sidx] = lo;
}

// ---- phase B: per-bin scatter into node buckets; pad buckets to x4 ----
__global__ __launch_bounds__(256) void bin_fill(const int* __restrict__ binc,
                                                const uint2* __restrict__ binbuf,
                                                int* __restrict__ fillc,
                                                unsigned* __restrict__ buck,
                                                int* __restrict__ ovf_cnt,
                                                uint2* __restrict__ ovf) {
    __shared__ int lcnt[256];
    const int tid = threadIdx.x;
    const int bin = blockIdx.x;
    lcnt[tid] = 0;
    __syncthreads();
    int n = binc[bin];
    if (n > BCAP) n = BCAP;
    const uint2* bp = binbuf + (size_t)bin * BCAP;
    for (int i = tid; i < n; i += 256) {
        uint2 q = bp[i];
        int d = (int)q.x;
        int p = atomicAdd(&lcnt[d & 255], 1);
        if (p < CAP) {
            buck[(size_t)d * CAP + p] = q.y;
        } else {
            int o = atomicAdd(ovf_cnt, 1);
            ovf[o] = q;
        }
    }
    __syncthreads();
    int node = bin * 256 + tid;
    if (node < NN) {
        int c = lcnt[tid];
        if (c > CAP) c = CAP;
        int pc = (c + 3) & ~3;                       // pad to multiple of 4
        for (int p = c; p < pc; ++p)
            buck[(size_t)node * CAP + p] = 0;        // src=0, w=+0.0h
        fillc[node] = pc;
    }
}

// ---- aggregate: half-wave per node, uniform 4-edge body, bf16 output ----
// grid 6250 x 256: 8 half-waves/block; lane t owns dims 4t..4t+3
__global__ __launch_bounds__(256) void aggregate(const unsigned* __restrict__ xb,
                                                 const int* __restrict__ fillc,
                                                 const unsigned* __restrict__ buck,
                                                 const int* __restrict__ ovf_cnt,
                                                 const uint2* __restrict__ ovf,
                                                 unsigned* __restrict__ aggb) {
    const int node = blockIdx.x * 8 + (threadIdx.x >> 5);
    const int t = threadIdx.x & 31;
    int cnt = fillc[node];                 // multiple of 4, <= CAP
    if (cnt > CAP) cnt = CAP;
    const uint4* bp4 = (const uint4*)(buck + (size_t)node * CAP);
    const uint2* x2 = (const uint2*)xb;
    float4 acc = {0.f, 0.f, 0.f, 0.f};
    int n4 = cnt >> 2;
    for (int i = 0; i < n4; ++i) {
        uint4 q = bp4[i];
        uint2 u0 = x2[(size_t)(q.x >> 16) * 32 + t];
        uint2 u1 = x2[(size_t)(q.y >> 16) * 32 + t];
        uint2 u2 = x2[(size_t)(q.z >> 16) * 32 + t];
        uint2 u3 = x2[(size_t)(q.w >> 16) * 32 + t];
        float w0 = __half2float(__ushort_as_half((ushort)(q.x & 0xffffu)));
        float w1 = __half2float(__ushort_as_half((ushort)(q.y & 0xffffu)));
        float w2 = __half2float(__ushort_as_half((ushort)(q.z & 0xffffu)));
        float w3 = __half2float(__ushort_as_half((ushort)(q.w & 0xffffu)));
        acc.x += __uint_as_float(u0.x << 16) * w0;
        acc.y += __uint_as_float(u0.x & 0xffff0000u) * w0;
        acc.z += __uint_as_float(u0.y << 16) * w0;
        acc.w += __uint_as_float(u0.y & 0xffff0000u) * w0;
        acc.x += __uint_as_float(u1.x << 16) * w1;
        acc.y += __uint_as_float(u1.x & 0xffff0000u) * w1;
        acc.z += __uint_as_float(u1.y << 16) * w1;
        acc.w += __uint_as_float(u1.y & 0xffff0000u) * w1;
        acc.x += __uint_as_float(u2.x << 16) * w2;
        acc.y += __uint_as_float(u2.x & 0xffff0000u) * w2;
        acc.z += __uint_as_float(u2.y << 16) * w2;
        acc.w += __uint_as_float(u2.y & 0xffff0000u) * w2;
        acc.x += __uint_as_float(u3.x << 16) * w3;
        acc.y += __uint_as_float(u3.x & 0xffff0000u) * w3;
        acc.z += __uint_as_float(u3.y << 16) * w3;
        acc.w += __uint_as_float(u3.y & 0xffff0000u) * w3;
    }
    // overflow entries (statistically never; correctness net)
    int n = *ovf_cnt;
    for (int o = 0; o < n; ++o) {
        uint2 q = ovf[o];
        if ((int)q.x == node) {
            uint2 u = x2[(size_t)(q.y >> 16) * 32 + t];
            float w = __half2float(__ushort_as_half((ushort)(q.y & 0xffffu)));
            acc.x += __uint_as_float(u.x << 16) * w;
            acc.y += __uint_as_float(u.x & 0xffff0000u) * w;
            acc.z += __uint_as_float(u.y << 16) * w;
            acc.w += __uint_as_float(u.y & 0xffff0000u) * w;
        }
    }
    unsigned o0 = f2bf_rne(acc.x) | (f2bf_rne(acc.y) << 16);
    unsigned o1 = f2bf_rne(acc.z) | (f2bf_rne(acc.w) << 16);
    ((uint2*)aggb)[(size_t)node * 32 + t] = make_uint2(o0, o1);
}

// ---- GEMM: bf16 A direct, W hi+lo split (2-term), bias+relu ----
__global__ __launch_bounds__(256) void gemm_mfma(const unsigned* __restrict__ aggb,
                                                 const ushort* __restrict__ wsp,
                                                 const float* __restrict__ bias,
                                                 float* __restrict__ out) {
    __shared__ ushort wl[32768];
    const int tid = threadIdx.x;
    {
        const uint4* s = (const uint4*)wsp;
        uint4* d = (uint4*)wl;
#pragma unroll
        for (int i = 0; i < 16; ++i)
            d[i * 256 + tid] = s[i * 256 + tid];
    }
    __syncthreads();

    const int wid = tid >> 6, lane = tid & 63;
    const int l15 = lane & 15, kg = lane >> 4;
    const int wrbase = blockIdx.x * GBM + wid * 32;

    f32x4 acc[2][8];
    const f32x4 fz = {0.f, 0.f, 0.f, 0.f};
#pragma unroll
    for (int m = 0; m < 2; ++m)
#pragma unroll
        for (int n = 0; n < 8; ++n) acc[m][n] = fz;

    int arow0 = wrbase + l15;
    int arow1 = wrbase + 16 + l15;
    // uint index: 64 uints per row; k-group kg owns bf16 k = kg*8.. -> uint kg*4
    const unsigned* a0p = aggb + (size_t)(arow0 < NN ? arow0 : NN - 1) * 64 + kg * 4;
    const unsigned* a1p = aggb + (size_t)(arow1 < NN ? arow1 : NN - 1) * 64 + kg * 4;

#pragma unroll
    for (int kk = 0; kk < 4; ++kk) {
        uint4 h0 = *(const uint4*)(a0p + kk * 16);   // k = kk*32 + kg*8 + [0..7]
        uint4 h1 = *(const uint4*)(a1p + kk * 16);
        bf16x8 a0 = *(bf16x8*)&h0;
        bf16x8 a1 = *(bf16x8*)&h1;

        int coff = ((kk * 4 + kg) ^ l15) * 8;
#pragma unroll
        for (int nf = 0; nf < 8; ++nf) {
            int bidx = (16 * nf + l15) * 128 + coff;
            bf16x8 bhi = *(const bf16x8*)&wl[bidx];
            bf16x8 blo = *(const bf16x8*)&wl[16384 + bidx];
            acc[0][nf] = __builtin_amdgcn_mfma_f32_16x16x32_bf16(a0, bhi, acc[0][nf], 0, 0, 0);
            acc[1][nf] = __builtin_amdgcn_mfma_f32_16x16x32_bf16(a1, bhi, acc[1][nf], 0, 0, 0);
            acc[0][nf] = __builtin_amdgcn_mfma_f32_16x16x32_bf16(a0, blo, acc[0][nf], 0, 0, 0);
            acc[1][nf] = __builtin_amdgcn_mfma_f32_16x16x32_bf16(a1, blo, acc[1][nf], 0, 0, 0);
        }
    }

    const int rofs = kg * 4;
#pragma unroll
    for (int nf = 0; nf < 8; ++nf) {
        int col = 16 * nf + l15;
        float bv = bias[col];
#pragma unroll
        for (int m = 0; m < 2; ++m) {
#pragma unroll
            for (int r = 0; r < 4; ++r) {
                int row = wrbase + 16 * m + rofs + r;
                if (row < NN) {
                    float h = acc[m][nf][r] + bv;
                    out[(size_t)row * D + col] = h > 0.f ? h : 0.f;
                }
            }
        }
    }
}

extern "C" void kernel_launch(void* const* d_in, const int* in_sizes, int n_in,
                              void* d_out, int out_size, void* d_ws, size_t ws_size,
                              hipStream_t stream) {
    const float* x    = (const float*)d_in[0];
    const int*   eidx = (const int*)d_in[1];   // [2, E] flat: src then dst
    const float* ew   = (const float*)d_in[2];
    const float* W    = (const float*)d_in[3];
    const float* bias = (const float*)d_in[4];
    float* out = (float*)d_out;

    const int* src = eidx;
    const int* dst = eidx + NE;

    // workspace layout (binbuf aliases aggb region: binbuf dead before aggregate writes)
    char* base = (char*)d_ws;
    unsigned* aggb   = (unsigned*)base;                         // NN*D bf16 = 12.8 MB
    uint2*    binbuf = (uint2*)base;                            // 6.4 MB (alias, dead first)
    unsigned* buck   = (unsigned*)(base + 25600000);            // NN*CAP*4 = 12.8 MB
    unsigned* xb     = (unsigned*)(base + 25600000 + 12800000); // 12.8 MB
    ushort*   wsp    = (ushort*)(base + 51200000);              // 64 KB
    int*      fillc   = (int*)(base + 51200000 + 65536);        // 200 KB
    int*      binc    = (int*)(base + 51200000 + 65536 + 200000);
    int*      ovf_cnt = (int*)((char*)binc + NBIN * 4);
    uint2*    ovf     = (uint2*)(base + 51200000 + 65536 + 200000 + 1024); // 512 KB

    hipMemsetAsync(binc, 0, NBIN * 4 + 4, stream);
    mega1<<<MEGA_GRID, 256, 0, stream>>>(x, W, src, dst, ew, xb, wsp, binc, binbuf, ovf_cnt, ovf);
    bin_fill<<<NBIN, 256, 0, stream>>>(binc, binbuf, fillc, buck, ovf_cnt, ovf);
    aggregate<<<6250, 256, 0, stream>>>(xb, fillc, buck, ovf_cnt, ovf, aggb);
    gemm_mfma<<<(NN + GBM - 1) / GBM, 256, 0, stream>>>(aggb, wsp, bias, out);
}